// Round 3
// baseline (2206.549 us; speedup 1.0000x reference)
//
#include <hip/hip_runtime.h>
#include <hip/hip_bf16.h>

#define NNODES 50000
#define NF 256
#define NH 4
#define NG 64
#define NCLS 10

typedef __hip_bfloat16 bf16;

// flags[0] = indices are int64 ; flags[1] = floats are bf16
__device__ inline float ldf(const void* p, int i, int isbf) {
    return isbf ? __bfloat162float(((const bf16*)p)[i]) : ((const float*)p)[i];
}
__device__ inline void stf(void* p, int i, float v, int isbf) {
    if (isbf) ((bf16*)p)[i] = __float2bfloat16(v);
    else ((float*)p)[i] = v;
}
__device__ inline void stOut(float& d, float v) { d = v; }
__device__ inline void stOut(bf16& d, float v) { d = __float2bfloat16(v); }
__device__ inline int clampN(int v) { return ((unsigned)v < (unsigned)NNODES) ? v : 0; }
__device__ inline int clampG(int v) { return ((unsigned)v < (unsigned)NG) ? v : 0; }

// ---- runtime dtype detection (one block) -----------------------------------
// int64: odd 32-bit words of edge_index are high halves == 0 (ids < 50000).
// bf16:  low 16 bits of each W1 word are a sane bf16 (|v| in [2^-37, 2^6] or 0);
//        for fp32 data those bits are mantissa garbage (P(all 256 sane) ~ 1e-197).
__global__ void detect_kernel(const int* __restrict__ ei, const unsigned* __restrict__ w1,
                              int* __restrict__ flags) {
    __shared__ int nzOdd, insane;
    if (threadIdx.x == 0) { nzOdd = 0; insane = 0; }
    __syncthreads();
    if (ei[2 * threadIdx.x + 1] != 0) atomicAdd(&nzOdd, 1);
    unsigned lo = w1[threadIdx.x] & 0xFFFFu;
    unsigned ex = (lo >> 7) & 0xFFu;
    bool sane = ((lo & 0x7FFFu) == 0u) || (ex >= 90u && ex <= 133u);
    if (!sane) atomicAdd(&insane, 1);
    __syncthreads();
    if (threadIdx.x == 0) {
        flags[0] = (nzOdd == 0) ? 1 : 0;
        flags[1] = (insane == 0) ? 1 : 0;
    }
}

__device__ inline void edge_sd(const int* __restrict__ ei, int e, int E, int is64,
                               int& s_, int& d_) {
    if (e < E) {
        if (is64) { s_ = ei[2 * e]; d_ = ei[2 * E + 2 * e]; }
        else      { s_ = ei[e];     d_ = ei[E + e]; }
    } else {
        s_ = d_ = e - E;  // self-loop
    }
    s_ = clampN(s_);
    d_ = clampN(d_);
}

// ---- GEMM: C[M,256] = A[M,256] @ B[256,256], fp32 acc, bf16 out ------------
// aFollows: A dtype follows flags[1] (inputs) vs always-bf16 (my ws buffers)
__global__ void gemm_tiled(const void* __restrict__ A, const void* __restrict__ Bm,
                           bf16* __restrict__ Cm, int M, const int* __restrict__ flags,
                           int aFollows) {
    __shared__ float As[32][33];
    __shared__ float Bs[32][33];
    const int K = NF, Nout = NF;
    int isbf = flags[1];
    int aIsBf = aFollows ? isbf : 1;
    int tx = threadIdx.x;          // 0..31
    int ty = threadIdx.y;          // 0..7
    int row0 = blockIdx.y * 32;
    int col0 = blockIdx.x * 32;
    float acc[4] = {0.f, 0.f, 0.f, 0.f};
    for (int kt = 0; kt < K; kt += 32) {
        #pragma unroll
        for (int i = 0; i < 4; i++) {
            int r = ty + i * 8;
            int grow = row0 + r;
            As[r][tx] = (grow < M) ? ldf(A, grow * K + kt + tx, aIsBf) : 0.f;
            Bs[r][tx] = ldf(Bm, (kt + r) * Nout + col0 + tx, isbf);
        }
        __syncthreads();
        #pragma unroll
        for (int kk = 0; kk < 32; kk++) {
            float b = Bs[kk][tx];
            acc[0] += As[ty][kk] * b;
            acc[1] += As[ty + 8][kk] * b;
            acc[2] += As[ty + 16][kk] * b;
            acc[3] += As[ty + 24][kk] * b;
        }
        __syncthreads();
    }
    #pragma unroll
    for (int i = 0; i < 4; i++) {
        int grow = row0 + ty + i * 8;
        if (grow < M) Cm[grow * Nout + col0 + tx] = __float2bfloat16(acc[i]);
    }
}

// ---- per-node attention logits ---------------------------------------------
__global__ void att_kernel(const bf16* __restrict__ h, const void* __restrict__ att_s,
                           const void* __restrict__ att_d,
                           float* __restrict__ a_src, float* __restrict__ a_dst,
                           const int* __restrict__ flags) {
    int isbf = flags[1];
    int n = blockIdx.x;
    int t = threadIdx.x;  // 0..255 ; head = t>>6
    float hv = __bfloat162float(h[n * NF + t]);
    float vs = hv * ldf(att_s, t, isbf);
    float vd = hv * ldf(att_d, t, isbf);
    #pragma unroll
    for (int off = 32; off > 0; off >>= 1) {
        vs += __shfl_down(vs, off, 64);
        vd += __shfl_down(vd, off, 64);
    }
    if ((t & 63) == 0) {
        a_src[n * NH + (t >> 6)] = vs;
        a_dst[n * NH + (t >> 6)] = vd;
    }
}

__device__ inline float leaky_clamp(float v) {
    v = v > 0.f ? v : 0.2f * v;
    return fminf(fmaxf(v, -30.f), 30.f);
}

// softmax is shift-invariant; |e| <= 30 by clamp so no max pass needed
__global__ void edge_sum_kernel(const int* __restrict__ ei,
                                const float* __restrict__ a_src, const float* __restrict__ a_dst,
                                float* __restrict__ ssum, int E, int total,
                                const int* __restrict__ flags) {
    int i = blockIdx.x * blockDim.x + threadIdx.x;
    if (i >= total) return;
    int is64 = flags[0];
    int e = i >> 2, hh = i & 3;
    int s_, d_;
    edge_sd(ei, e, E, is64, s_, d_);
    float v = leaky_clamp(a_src[s_ * NH + hh] + a_dst[d_ * NH + hh]);
    atomicAdd(&ssum[d_ * NH + hh], expf(v));
}

__global__ void edge_agg_kernel(const int* __restrict__ ei,
                                const float* __restrict__ a_src, const float* __restrict__ a_dst,
                                const float* __restrict__ ssum, const bf16* __restrict__ h,
                                float* __restrict__ agg, int E, const int* __restrict__ flags) {
    int e = blockIdx.x;
    int t = threadIdx.x;  // 0..255
    int is64 = flags[0];
    int s_, d_;
    edge_sd(ei, e, E, is64, s_, d_);
    int hh = t >> 6;
    float v = leaky_clamp(a_src[s_ * NH + hh] + a_dst[d_ * NH + hh]);
    float alpha = expf(v) / fmaxf(ssum[d_ * NH + hh], 1e-30f);
    atomicAdd(&agg[d_ * NF + t], alpha * __bfloat162float(h[s_ * NF + t]));
}

// agg = elu(agg + b) + resid     (in place)
__global__ void finalize_kernel(float* __restrict__ agg, const void* __restrict__ b,
                                const void* __restrict__ resid, int total,
                                const int* __restrict__ flags, int residFollows) {
    int i = blockIdx.x * blockDim.x + threadIdx.x;
    if (i >= total) return;
    int isbf = flags[1];
    int rIsBf = residFollows ? isbf : 1;
    float v = agg[i] + ldf(b, i & (NF - 1), isbf);
    v = v > 0.f ? v : (expf(v) - 1.0f);
    agg[i] = v + ldf(resid, i, rIsBf);
}

__global__ void bn_stats_kernel(const float* __restrict__ x, float* __restrict__ bsum,
                                float* __restrict__ bsumsq) {
    int f = threadIdx.x;  // 256
    float s = 0.f, sq = 0.f;
    for (int r = blockIdx.x; r < NNODES; r += gridDim.x) {
        float v = x[r * NF + f];
        s += v;
        sq += v * v;
    }
    atomicAdd(&bsum[f], s);
    atomicAdd(&bsumsq[f], sq);
}

template <typename OT>
__global__ void bn_norm_kernel(const float* __restrict__ x, const float* __restrict__ bsum,
                               const float* __restrict__ bsumsq,
                               const void* __restrict__ gamma, const void* __restrict__ beta,
                               OT* __restrict__ out, int total, const int* __restrict__ flags) {
    int i = blockIdx.x * blockDim.x + threadIdx.x;
    if (i >= total) return;
    int isbf = flags[1];
    const float invN = 1.0f / (float)NNODES;
    int f = i & (NF - 1);
    float mu = bsum[f] * invN;
    float var = fmaxf(bsumsq[f] * invN - mu * mu, 0.f);
    float v = (x[i] - mu) * rsqrtf(var + 1e-5f);
    stOut(out[i], ldf(gamma, f, isbf) * v + ldf(beta, f, isbf));
}

__global__ void pool_kernel(const float* __restrict__ x, const int* __restrict__ bt,
                            float* __restrict__ pooled, float* __restrict__ cnt, int total,
                            const int* __restrict__ flags) {
    int i = blockIdx.x * blockDim.x + threadIdx.x;
    if (i >= total) return;
    int is64 = flags[0];
    int n = i >> 8, f = i & (NF - 1);
    int g = clampG(is64 ? bt[2 * n] : bt[n]);
    atomicAdd(&pooled[g * NF + f], x[i]);
    if (f == 0) atomicAdd(&cnt[g], 1.0f);
}

__global__ void head_kernel(const float* __restrict__ pooled, const float* __restrict__ cnt,
                            const void* __restrict__ fc1w, const void* __restrict__ fc1b,
                            const void* __restrict__ fc2w, const void* __restrict__ fc2b,
                            void* __restrict__ out, const int* __restrict__ flags) {
    int g = blockIdx.x;   // 64
    int t = threadIdx.x;  // 64
    int isbf = flags[1];
    __shared__ float p[NF];
    __shared__ float z[64];
    __shared__ float logits[NCLS];
    __shared__ float lse;
    float c = fmaxf(cnt[g], 1.f);
    float invc = 1.f / c;
    for (int i = t; i < NF; i += 64) p[i] = pooled[g * NF + i] * invc;
    __syncthreads();
    float acc = ldf(fc1b, t, isbf);
    for (int k = 0; k < NF; k++) acc += p[k] * ldf(fc1w, k * 64 + t, isbf);
    z[t] = acc > 0.f ? acc : 0.f;
    __syncthreads();
    if (t < NCLS) {
        float a2 = ldf(fc2b, t, isbf);
        for (int k = 0; k < 64; k++) a2 += z[k] * ldf(fc2w, k * NCLS + t, isbf);
        logits[t] = a2;
    }
    __syncthreads();
    if (t == 0) {
        float mx = logits[0];
        for (int j = 1; j < NCLS; j++) mx = fmaxf(mx, logits[j]);
        float se = 0.f;
        for (int j = 0; j < NCLS; j++) se += expf(logits[j] - mx);
        lse = mx + logf(se);
    }
    __syncthreads();
    if (t < NCLS) stf(out, g * NCLS + t, logits[t] - lse, isbf);
}

extern "C" void kernel_launch(void* const* d_in, const int* in_sizes, int n_in,
                              void* d_out, int out_size, void* d_ws, size_t ws_size,
                              hipStream_t stream) {
    const void* x = d_in[0];
    const int* edge_index = (const int*)d_in[1];
    const int* batch = (const int*)d_in[2];
    const void* W1 = d_in[3];
    const void* att_src1 = d_in[4];
    const void* att_dst1 = d_in[5];
    const void* b1 = d_in[6];
    const void* gamma1 = d_in[7];
    const void* beta1 = d_in[8];
    const void* W2 = d_in[9];
    const void* att_src2 = d_in[10];
    const void* att_dst2 = d_in[11];
    const void* b2 = d_in[12];
    const void* gamma2 = d_in[13];
    const void* beta2 = d_in[14];
    const void* fc1w = d_in[15];
    const void* fc1b = d_in[16];
    const void* fc2w = d_in[17];
    const void* fc2b = d_in[18];

    const int E = in_sizes[1] / 2;     // 400000
    const int ET = E + NNODES;         // + self-loops
    const int NE = NNODES * NF;
    const int NNH = NNODES * NH;

    // ---- workspace layout (~105 MB) ----
    float* ws = (float*)d_ws;
    float* agg = ws;                       // N*256 fp32
    float* asrc = agg + NE;                // N*4
    float* adst = asrc + NNH;              // N*4
    float* sbuf = adst + NNH;              // N*4
    float* bnsum = sbuf + NNH;             // 256
    float* bnsq = bnsum + NF;              // 256
    float* pooled = bnsq + NF;             // 64*256
    float* cntb = pooled + NG * NF;        // 64
    int* flags = (int*)(cntb + NG);        // 2 (+pad 16)
    bf16* hb = (bf16*)(flags + 16);        // N*256 bf16
    bf16* l1ob = hb + NE;                  // N*256 bf16

    dim3 gb(32, 8);
    dim3 gemm_grid(NF / 32, (NNODES + 31) / 32);

    detect_kernel<<<1, 256, 0, stream>>>(edge_index, (const unsigned*)W1, flags);

    // ================= layer 1 =================
    gemm_tiled<<<gemm_grid, gb, 0, stream>>>(x, W1, hb, NNODES, flags, 1);
    att_kernel<<<NNODES, 256, 0, stream>>>(hb, att_src1, att_dst1, asrc, adst, flags);
    hipMemsetAsync(sbuf, 0, sizeof(float) * NNH, stream);
    edge_sum_kernel<<<(ET * NH + 255) / 256, 256, 0, stream>>>(edge_index, asrc, adst, sbuf, E, ET * NH, flags);
    hipMemsetAsync(agg, 0, sizeof(float) * NE, stream);
    edge_agg_kernel<<<ET, 256, 0, stream>>>(edge_index, asrc, adst, sbuf, hb, agg, E, flags);
    finalize_kernel<<<(NE + 255) / 256, 256, 0, stream>>>(agg, b1, x, NE, flags, 1);
    hipMemsetAsync(bnsum, 0, sizeof(float) * 2 * NF, stream);
    bn_stats_kernel<<<512, 256, 0, stream>>>(agg, bnsum, bnsq);
    bn_norm_kernel<bf16><<<(NE + 255) / 256, 256, 0, stream>>>(agg, bnsum, bnsq, gamma1, beta1, l1ob, NE, flags);

    // ================= layer 2 =================
    gemm_tiled<<<gemm_grid, gb, 0, stream>>>(l1ob, W2, hb, NNODES, flags, 0);
    att_kernel<<<NNODES, 256, 0, stream>>>(hb, att_src2, att_dst2, asrc, adst, flags);
    hipMemsetAsync(sbuf, 0, sizeof(float) * NNH, stream);
    edge_sum_kernel<<<(ET * NH + 255) / 256, 256, 0, stream>>>(edge_index, asrc, adst, sbuf, E, ET * NH, flags);
    hipMemsetAsync(agg, 0, sizeof(float) * NE, stream);
    edge_agg_kernel<<<ET, 256, 0, stream>>>(edge_index, asrc, adst, sbuf, hb, agg, E, flags);
    finalize_kernel<<<(NE + 255) / 256, 256, 0, stream>>>(agg, b2, l1ob, NE, flags, 0);
    hipMemsetAsync(bnsum, 0, sizeof(float) * 2 * NF, stream);
    bn_stats_kernel<<<512, 256, 0, stream>>>(agg, bnsum, bnsq);
    bn_norm_kernel<float><<<(NE + 255) / 256, 256, 0, stream>>>(agg, bnsum, bnsq, gamma2, beta2, agg, NE, flags);

    // ================= pool + head =================
    hipMemsetAsync(pooled, 0, sizeof(float) * (NG * NF + NG), stream);
    pool_kernel<<<(NE + 255) / 256, 256, 0, stream>>>(agg, batch, pooled, cntb, NE, flags);
    head_kernel<<<NG, 64, 0, stream>>>(pooled, cntb, fc1w, fc1b, fc2w, fc2b, d_out, flags);
}

// Round 4
// 1505.617 us; speedup vs baseline: 1.4655x; 1.4655x over previous
//
#include <hip/hip_runtime.h>
#include <hip/hip_bf16.h>

#define NNODES 50000
#define NF 256
#define NH 4
#define NG 64
#define NCLS 10

typedef __hip_bfloat16 bf16;

// flags[0] = indices are int64 ; flags[1] = floats are bf16
__device__ inline float ldf(const void* p, int i, int isbf) {
    return isbf ? __bfloat162float(((const bf16*)p)[i]) : ((const float*)p)[i];
}
__device__ inline void stf(void* p, int i, float v, int isbf) {
    if (isbf) ((bf16*)p)[i] = __float2bfloat16(v);
    else ((float*)p)[i] = v;
}
__device__ inline void stOut(float& d, float v) { d = v; }
__device__ inline void stOut(bf16& d, float v) { d = __float2bfloat16(v); }
__device__ inline int clampN(int v) { return ((unsigned)v < (unsigned)NNODES) ? v : 0; }
__device__ inline int clampG(int v) { return ((unsigned)v < (unsigned)NG) ? v : 0; }

__global__ void detect_kernel(const int* __restrict__ ei, const unsigned* __restrict__ w1,
                              int* __restrict__ flags) {
    __shared__ int nzOdd, insane;
    if (threadIdx.x == 0) { nzOdd = 0; insane = 0; }
    __syncthreads();
    if (ei[2 * threadIdx.x + 1] != 0) atomicAdd(&nzOdd, 1);
    unsigned lo = w1[threadIdx.x] & 0xFFFFu;
    unsigned ex = (lo >> 7) & 0xFFu;
    bool sane = ((lo & 0x7FFFu) == 0u) || (ex >= 90u && ex <= 133u);
    if (!sane) atomicAdd(&insane, 1);
    __syncthreads();
    if (threadIdx.x == 0) {
        flags[0] = (nzOdd == 0) ? 1 : 0;
        flags[1] = (insane == 0) ? 1 : 0;
    }
}

__device__ inline void edge_sd(const int* __restrict__ ei, int e, int E, int is64,
                               int& s_, int& d_) {
    if (e < E) {
        if (is64) { s_ = ei[2 * e]; d_ = ei[2 * E + 2 * e]; }
        else      { s_ = ei[e];     d_ = ei[E + e]; }
    } else {
        s_ = d_ = e - E;  // self-loop
    }
    s_ = clampN(s_);
    d_ = clampN(d_);
}

// ======================= CSR build (once, reused both layers) ================
__global__ void deg_kernel(const int* __restrict__ ei, int* __restrict__ deg,
                           int E, int ET, const int* __restrict__ flags) {
    int e = blockIdx.x * 256 + threadIdx.x;
    if (e >= ET) return;
    int s_, d_;
    edge_sd(ei, e, E, flags[0], s_, d_);
    atomicAdd(&deg[d_], 1);
}

__global__ void scan1_kernel(const int* __restrict__ deg, int* __restrict__ eprefix,
                             int* __restrict__ bsums, int n) {
    __shared__ int sc[256];
    int t = threadIdx.x, i = blockIdx.x * 256 + t;
    int val = (i < n) ? deg[i] : 0;
    sc[t] = val;
    __syncthreads();
    for (int off = 1; off < 256; off <<= 1) {
        int tmp = (t >= off) ? sc[t - off] : 0;
        __syncthreads();
        sc[t] += tmp;
        __syncthreads();
    }
    if (i < n) eprefix[i] = sc[t] - val;
    if (t == 255) bsums[blockIdx.x] = sc[255];
}

__global__ void scan2_kernel(const int* __restrict__ bsums, int* __restrict__ boffs, int nb) {
    __shared__ int sc[256];
    int t = threadIdx.x;
    int val = (t < nb) ? bsums[t] : 0;
    sc[t] = val;
    __syncthreads();
    for (int off = 1; off < 256; off <<= 1) {
        int tmp = (t >= off) ? sc[t - off] : 0;
        __syncthreads();
        sc[t] += tmp;
        __syncthreads();
    }
    if (t < nb) boffs[t] = sc[t] - val;
}

__global__ void scan3_kernel(const int* __restrict__ eprefix, const int* __restrict__ boffs,
                             int* __restrict__ rowptr, int n, int ET) {
    int i = blockIdx.x * 256 + threadIdx.x;
    if (i < n) rowptr[i] = eprefix[i] + boffs[blockIdx.x];
    if (i == n) rowptr[n] = ET;
}

__global__ void scatter_kernel(const int* __restrict__ ei, const int* __restrict__ rowptr,
                               int* __restrict__ cursor, int* __restrict__ srcs,
                               int E, int ET, const int* __restrict__ flags) {
    int e = blockIdx.x * 256 + threadIdx.x;
    if (e >= ET) return;
    int s_, d_;
    edge_sd(ei, e, E, flags[0], s_, d_);
    int pos = atomicAdd(&cursor[d_], 1);
    srcs[rowptr[d_] + pos] = s_;
}

// ======================= graph boundaries for pooling =======================
__global__ void gcnt_kernel(const int* __restrict__ bt, int* __restrict__ gcnt,
                            const int* __restrict__ flags) {
    int n = blockIdx.x * 256 + threadIdx.x;
    if (n >= NNODES) return;
    int g = clampG(flags[0] ? bt[2 * n] : bt[n]);
    atomicAdd(&gcnt[g], 1);
}

__global__ void goff_kernel(const int* __restrict__ gcnt, int* __restrict__ goff) {
    if (threadIdx.x == 0) {
        int acc = 0;
        for (int g = 0; g < NG; g++) { goff[g] = acc; acc += gcnt[g]; }
        goff[NG] = acc;
    }
}

// ---- GEMM: C[M,256] = A[M,256] @ B[256,256], fp32 acc, bf16 out ------------
__global__ void gemm_tiled(const void* __restrict__ A, const void* __restrict__ Bm,
                           bf16* __restrict__ Cm, int M, const int* __restrict__ flags,
                           int aFollows) {
    __shared__ float As[32][33];
    __shared__ float Bs[32][33];
    const int K = NF, Nout = NF;
    int isbf = flags[1];
    int aIsBf = aFollows ? isbf : 1;
    int tx = threadIdx.x;
    int ty = threadIdx.y;
    int row0 = blockIdx.y * 32;
    int col0 = blockIdx.x * 32;
    float acc[4] = {0.f, 0.f, 0.f, 0.f};
    for (int kt = 0; kt < K; kt += 32) {
        #pragma unroll
        for (int i = 0; i < 4; i++) {
            int r = ty + i * 8;
            int grow = row0 + r;
            As[r][tx] = (grow < M) ? ldf(A, grow * K + kt + tx, aIsBf) : 0.f;
            Bs[r][tx] = ldf(Bm, (kt + r) * Nout + col0 + tx, isbf);
        }
        __syncthreads();
        #pragma unroll
        for (int kk = 0; kk < 32; kk++) {
            float b = Bs[kk][tx];
            acc[0] += As[ty][kk] * b;
            acc[1] += As[ty + 8][kk] * b;
            acc[2] += As[ty + 16][kk] * b;
            acc[3] += As[ty + 24][kk] * b;
        }
        __syncthreads();
    }
    #pragma unroll
    for (int i = 0; i < 4; i++) {
        int grow = row0 + ty + i * 8;
        if (grow < M) Cm[grow * Nout + col0 + tx] = __float2bfloat16(acc[i]);
    }
}

// ---- per-node attention logits ---------------------------------------------
__global__ void att_kernel(const bf16* __restrict__ h, const void* __restrict__ att_s,
                           const void* __restrict__ att_d,
                           float* __restrict__ a_src, float* __restrict__ a_dst,
                           const int* __restrict__ flags) {
    int isbf = flags[1];
    int n = blockIdx.x;
    int t = threadIdx.x;
    float hv = __bfloat162float(h[n * NF + t]);
    float vs = hv * ldf(att_s, t, isbf);
    float vd = hv * ldf(att_d, t, isbf);
    #pragma unroll
    for (int off = 32; off > 0; off >>= 1) {
        vs += __shfl_down(vs, off, 64);
        vd += __shfl_down(vd, off, 64);
    }
    if ((t & 63) == 0) {
        a_src[n * NH + (t >> 6)] = vs;
        a_dst[n * NH + (t >> 6)] = vd;
    }
}

__device__ inline float leaky_clamp(float v) {
    v = v > 0.f ? v : 0.2f * v;
    return fminf(fmaxf(v, -30.f), 30.f);
}

// ---- fused per-dst softmax + aggregate + bias + ELU + residual -------------
// one block per dst node; no atomics, writes agg[d] exactly once
__global__ void agg_csr_kernel(const int* __restrict__ rowptr, const int* __restrict__ srcs,
                               const float* __restrict__ asrc, const float* __restrict__ adst,
                               const bf16* __restrict__ h, const void* __restrict__ bias,
                               const void* __restrict__ resid, float* __restrict__ agg,
                               const int* __restrict__ flags, int residFollows) {
    int d = blockIdx.x;
    int t = threadIdx.x;        // 0..255
    int hh = t >> 6;            // head = wave id
    int lane = t & 63;
    int isbf = flags[1];
    int rIsBf = residFollows ? isbf : 1;
    int beg = rowptr[d], end = rowptr[d + 1];
    float ad = adst[d * NH + hh];
    __shared__ float sden[NH];
    // phase 1: softmax denominator per head (wave hh handles head hh)
    float part = 0.f;
    for (int k = beg + lane; k < end; k += 64) {
        int s = srcs[k];
        part += expf(leaky_clamp(asrc[s * NH + hh] + ad));
    }
    #pragma unroll
    for (int off = 32; off > 0; off >>= 1) part += __shfl_down(part, off, 64);
    if (lane == 0) sden[hh] = part;
    __syncthreads();
    float inv = 1.f / fmaxf(sden[hh], 1e-30f);
    // phase 2: weighted gather
    float acc = 0.f;
    for (int k = beg; k < end; k++) {
        int s = srcs[k];
        float al = expf(leaky_clamp(asrc[s * NH + hh] + ad)) * inv;
        acc += al * __bfloat162float(h[s * NF + t]);
    }
    // epilogue: + bias, ELU, + residual
    float v = acc + ldf(bias, t, isbf);
    v = v > 0.f ? v : (expf(v) - 1.0f);
    agg[d * NF + t] = v + ldf(resid, d * NF + t, rIsBf);
}

__global__ void bn_stats_kernel(const float* __restrict__ x, float* __restrict__ bsum,
                                float* __restrict__ bsumsq) {
    int f = threadIdx.x;
    float s = 0.f, sq = 0.f;
    for (int r = blockIdx.x; r < NNODES; r += gridDim.x) {
        float v = x[r * NF + f];
        s += v;
        sq += v * v;
    }
    atomicAdd(&bsum[f], s);
    atomicAdd(&bsumsq[f], sq);
}

template <typename OT>
__global__ void bn_norm_kernel(const float* __restrict__ x, const float* __restrict__ bsum,
                               const float* __restrict__ bsumsq,
                               const void* __restrict__ gamma, const void* __restrict__ beta,
                               OT* __restrict__ out, int total, const int* __restrict__ flags) {
    int i = blockIdx.x * blockDim.x + threadIdx.x;
    if (i >= total) return;
    int isbf = flags[1];
    const float invN = 1.0f / (float)NNODES;
    int f = i & (NF - 1);
    float mu = bsum[f] * invN;
    float var = fmaxf(bsumsq[f] * invN - mu * mu, 0.f);
    float v = (x[i] - mu) * rsqrtf(var + 1e-5f);
    stOut(out[i], ldf(gamma, f, isbf) * v + ldf(beta, f, isbf));
}

// ---- pooling: contiguous node slices per graph (batch is sorted) -----------
__global__ void pool2_kernel(const float* __restrict__ x, const int* __restrict__ goff,
                             float* __restrict__ pooled) {
    int g = blockIdx.x >> 3, c = blockIdx.x & 7, t = threadIdx.x;
    int beg = goff[g], end = goff[g + 1];
    int len = end - beg;
    if (len <= 0) return;
    int chunk = (len + 7) >> 3;
    int s0 = beg + c * chunk;
    int s1 = min(s0 + chunk, end);
    if (s0 >= s1) return;
    float acc = 0.f;
    for (int n = s0; n < s1; n++) acc += x[n * NF + t];
    atomicAdd(&pooled[g * NF + t], acc);
}

__global__ void head_kernel(const float* __restrict__ pooled, const int* __restrict__ gcnt,
                            const void* __restrict__ fc1w, const void* __restrict__ fc1b,
                            const void* __restrict__ fc2w, const void* __restrict__ fc2b,
                            void* __restrict__ out, const int* __restrict__ flags) {
    int g = blockIdx.x;
    int t = threadIdx.x;  // 64
    int isbf = flags[1];
    __shared__ float p[NF];
    __shared__ float z[64];
    __shared__ float logits[NCLS];
    __shared__ float lse;
    float c = fmaxf((float)gcnt[g], 1.f);
    float invc = 1.f / c;
    for (int i = t; i < NF; i += 64) p[i] = pooled[g * NF + i] * invc;
    __syncthreads();
    float acc = ldf(fc1b, t, isbf);
    for (int k = 0; k < NF; k++) acc += p[k] * ldf(fc1w, k * 64 + t, isbf);
    z[t] = acc > 0.f ? acc : 0.f;
    __syncthreads();
    if (t < NCLS) {
        float a2 = ldf(fc2b, t, isbf);
        for (int k = 0; k < 64; k++) a2 += z[k] * ldf(fc2w, k * NCLS + t, isbf);
        logits[t] = a2;
    }
    __syncthreads();
    if (t == 0) {
        float mx = logits[0];
        for (int j = 1; j < NCLS; j++) mx = fmaxf(mx, logits[j]);
        float se = 0.f;
        for (int j = 0; j < NCLS; j++) se += expf(logits[j] - mx);
        lse = mx + logf(se);
    }
    __syncthreads();
    if (t < NCLS) stf(out, g * NCLS + t, logits[t] - lse, isbf);
}

extern "C" void kernel_launch(void* const* d_in, const int* in_sizes, int n_in,
                              void* d_out, int out_size, void* d_ws, size_t ws_size,
                              hipStream_t stream) {
    const void* x = d_in[0];
    const int* edge_index = (const int*)d_in[1];
    const int* batch = (const int*)d_in[2];
    const void* W1 = d_in[3];
    const void* att_src1 = d_in[4];
    const void* att_dst1 = d_in[5];
    const void* b1 = d_in[6];
    const void* gamma1 = d_in[7];
    const void* beta1 = d_in[8];
    const void* W2 = d_in[9];
    const void* att_src2 = d_in[10];
    const void* att_dst2 = d_in[11];
    const void* b2 = d_in[12];
    const void* gamma2 = d_in[13];
    const void* beta2 = d_in[14];
    const void* fc1w = d_in[15];
    const void* fc1b = d_in[16];
    const void* fc2w = d_in[17];
    const void* fc2b = d_in[18];

    const int E = in_sizes[1] / 2;     // 400000
    const int ET = E + NNODES;         // + self-loops
    const int NE = NNODES * NF;
    const int NNH = NNODES * NH;
    const int NB = (NNODES + 255) / 256;        // 196
    const int NB1 = (NNODES + 1 + 255) / 256;   // covers i == NNODES

    // ---- workspace layout ----
    float* ws = (float*)d_ws;
    float* agg = ws;                       // N*256 fp32
    float* asrc = agg + NE;                // N*4
    float* adst = asrc + NNH;              // N*4
    int* flags = (int*)(adst + NNH);       // 16
    bf16* hb = (bf16*)(flags + 16);        // N*256 bf16
    bf16* l1ob = hb + NE;                  // N*256 bf16
    int* rowptr = (int*)(l1ob + NE);       // N+1 (+pad)
    int* srcs = rowptr + NNODES + 16;      // ET
    int* goff = srcs + ET + 16;            // NG+1
    // zero region (single memset): deg, cursor, gcnt, pooled, bnstat
    int* deg = goff + NG + 1 + 14;
    int* cursor = deg + NNODES;
    int* gcnt = cursor + NNODES;
    float* pooled = (float*)(gcnt + NG);   // 64*256
    float* bnstat = pooled + NG * NF;      // 4*256: bnsum1,bnsq1,bnsum2,bnsq2
    size_t zero_bytes = (size_t)(2 * NNODES + NG) * 4 + (size_t)(NG * NF + 4 * NF) * 4;
    // scratch for scan aliased onto asrc/adst (written later by att_kernel)
    int* eprefix = (int*)asrc;             // N
    int* bsums = eprefix + NNODES + 16;    // 256
    int* boffs = bsums + 256;              // 256

    float* bnsum1 = bnstat;
    float* bnsq1 = bnstat + NF;
    float* bnsum2 = bnstat + 2 * NF;
    float* bnsq2 = bnstat + 3 * NF;

    dim3 gb(32, 8);
    dim3 gemm_grid(NF / 32, (NNODES + 31) / 32);

    detect_kernel<<<1, 256, 0, stream>>>(edge_index, (const unsigned*)W1, flags);
    hipMemsetAsync(deg, 0, zero_bytes, stream);

    // ---- CSR build + graph boundaries (reused by both layers) ----
    deg_kernel<<<(ET + 255) / 256, 256, 0, stream>>>(edge_index, deg, E, ET, flags);
    scan1_kernel<<<NB, 256, 0, stream>>>(deg, eprefix, bsums, NNODES);
    scan2_kernel<<<1, 256, 0, stream>>>(bsums, boffs, NB);
    scan3_kernel<<<NB1, 256, 0, stream>>>(eprefix, boffs, rowptr, NNODES, ET);
    scatter_kernel<<<(ET + 255) / 256, 256, 0, stream>>>(edge_index, rowptr, cursor, srcs, E, ET, flags);
    gcnt_kernel<<<NB, 256, 0, stream>>>(batch, gcnt, flags);
    goff_kernel<<<1, 64, 0, stream>>>(gcnt, goff);

    // ================= layer 1 =================
    gemm_tiled<<<gemm_grid, gb, 0, stream>>>(x, W1, hb, NNODES, flags, 1);
    att_kernel<<<NNODES, 256, 0, stream>>>(hb, att_src1, att_dst1, asrc, adst, flags);
    agg_csr_kernel<<<NNODES, 256, 0, stream>>>(rowptr, srcs, asrc, adst, hb, b1, x, agg, flags, 1);
    bn_stats_kernel<<<512, 256, 0, stream>>>(agg, bnsum1, bnsq1);
    bn_norm_kernel<bf16><<<(NE + 255) / 256, 256, 0, stream>>>(agg, bnsum1, bnsq1, gamma1, beta1, l1ob, NE, flags);

    // ================= layer 2 =================
    gemm_tiled<<<gemm_grid, gb, 0, stream>>>(l1ob, W2, hb, NNODES, flags, 0);
    att_kernel<<<NNODES, 256, 0, stream>>>(hb, att_src2, att_dst2, asrc, adst, flags);
    agg_csr_kernel<<<NNODES, 256, 0, stream>>>(rowptr, srcs, asrc, adst, hb, b2, l1ob, agg, flags, 0);
    bn_stats_kernel<<<512, 256, 0, stream>>>(agg, bnsum2, bnsq2);
    bn_norm_kernel<float><<<(NE + 255) / 256, 256, 0, stream>>>(agg, bnsum2, bnsq2, gamma2, beta2, agg, NE, flags);

    // ================= pool + head =================
    pool2_kernel<<<NG * 8, 256, 0, stream>>>(agg, goff, pooled);
    head_kernel<<<NG, 64, 0, stream>>>(pooled, gcnt, fc1w, fc1b, fc2w, fc2b, d_out, flags);
}

// Round 5
// 951.806 us; speedup vs baseline: 2.3183x; 1.5819x over previous
//
#include <hip/hip_runtime.h>
#include <hip/hip_bf16.h>

#define NNODES 50000
#define NF 256
#define NH 4
#define NG 64
#define NCLS 10
#define MPAD 50048  // NNODES rounded up to multiple of 64 (gemm row padding)

typedef __hip_bfloat16 bf16;
typedef __attribute__((ext_vector_type(8))) short short8;   // 8 bf16 = 4 VGPRs
typedef __attribute__((ext_vector_type(4))) float floatx4;  // MFMA accumulator

// flags[0] = indices are int64 ; flags[1] = floats are bf16
__device__ inline float ldf(const void* p, int i, int isbf) {
    return isbf ? __bfloat162float(((const bf16*)p)[i]) : ((const float*)p)[i];
}
__device__ inline void stf(void* p, int i, float v, int isbf) {
    if (isbf) ((bf16*)p)[i] = __float2bfloat16(v);
    else ((float*)p)[i] = v;
}
__device__ inline short f2bfbits(float v) {
    bf16 b = __float2bfloat16(v);
    return *reinterpret_cast<short*>(&b);
}
__device__ inline void stOut(float& d, float v) { d = v; }
__device__ inline void stOut(bf16& d, float v) { d = __float2bfloat16(v); }
__device__ inline int clampN(int v) { return ((unsigned)v < (unsigned)NNODES) ? v : 0; }
__device__ inline int clampG(int v) { return ((unsigned)v < (unsigned)NG) ? v : 0; }

__global__ void detect_kernel(const int* __restrict__ ei, const unsigned* __restrict__ w1,
                              int* __restrict__ flags) {
    __shared__ int nzOdd, insane;
    if (threadIdx.x == 0) { nzOdd = 0; insane = 0; }
    __syncthreads();
    if (ei[2 * threadIdx.x + 1] != 0) atomicAdd(&nzOdd, 1);
    unsigned lo = w1[threadIdx.x] & 0xFFFFu;
    unsigned ex = (lo >> 7) & 0xFFu;
    bool sane = ((lo & 0x7FFFu) == 0u) || (ex >= 90u && ex <= 133u);
    if (!sane) atomicAdd(&insane, 1);
    __syncthreads();
    if (threadIdx.x == 0) {
        flags[0] = (nzOdd == 0) ? 1 : 0;
        flags[1] = (insane == 0) ? 1 : 0;
    }
}

__device__ inline void edge_sd(const int* __restrict__ ei, int e, int E, int is64,
                               int& s_, int& d_) {
    if (e < E) {
        if (is64) { s_ = ei[2 * e]; d_ = ei[2 * E + 2 * e]; }
        else      { s_ = ei[e];     d_ = ei[E + e]; }
    } else {
        s_ = d_ = e - E;  // self-loop
    }
    s_ = clampN(s_);
    d_ = clampN(d_);
}

// ======================= CSR build (once, reused both layers) ================
__global__ void deg_kernel(const int* __restrict__ ei, int* __restrict__ deg,
                           int E, int ET, const int* __restrict__ flags) {
    int e = blockIdx.x * 256 + threadIdx.x;
    if (e >= ET) return;
    int s_, d_;
    edge_sd(ei, e, E, flags[0], s_, d_);
    atomicAdd(&deg[d_], 1);
}

__global__ void scan1_kernel(const int* __restrict__ deg, int* __restrict__ eprefix,
                             int* __restrict__ bsums, int n) {
    __shared__ int sc[256];
    int t = threadIdx.x, i = blockIdx.x * 256 + t;
    int val = (i < n) ? deg[i] : 0;
    sc[t] = val;
    __syncthreads();
    for (int off = 1; off < 256; off <<= 1) {
        int tmp = (t >= off) ? sc[t - off] : 0;
        __syncthreads();
        sc[t] += tmp;
        __syncthreads();
    }
    if (i < n) eprefix[i] = sc[t] - val;
    if (t == 255) bsums[blockIdx.x] = sc[255];
}

__global__ void scan2_kernel(const int* __restrict__ bsums, int* __restrict__ boffs, int nb) {
    __shared__ int sc[256];
    int t = threadIdx.x;
    int val = (t < nb) ? bsums[t] : 0;
    sc[t] = val;
    __syncthreads();
    for (int off = 1; off < 256; off <<= 1) {
        int tmp = (t >= off) ? sc[t - off] : 0;
        __syncthreads();
        sc[t] += tmp;
        __syncthreads();
    }
    if (t < nb) boffs[t] = sc[t] - val;
}

__global__ void scan3_kernel(const int* __restrict__ eprefix, const int* __restrict__ boffs,
                             int* __restrict__ rowptr, int n, int ET) {
    int i = blockIdx.x * 256 + threadIdx.x;
    if (i < n) rowptr[i] = eprefix[i] + boffs[blockIdx.x];
    if (i == n) rowptr[n] = ET;
}

__global__ void scatter_kernel(const int* __restrict__ ei, const int* __restrict__ rowptr,
                               int* __restrict__ cursor, int* __restrict__ srcs,
                               int E, int ET, const int* __restrict__ flags) {
    int e = blockIdx.x * 256 + threadIdx.x;
    if (e >= ET) return;
    int s_, d_;
    edge_sd(ei, e, E, flags[0], s_, d_);
    int pos = atomicAdd(&cursor[d_], 1);
    srcs[rowptr[d_] + pos] = s_;
}

// ======================= graph boundaries for pooling =======================
__global__ void gcnt_kernel(const int* __restrict__ bt, int* __restrict__ gcnt,
                            const int* __restrict__ flags) {
    int n = blockIdx.x * 256 + threadIdx.x;
    if (n >= NNODES) return;
    int g = clampG(flags[0] ? bt[2 * n] : bt[n]);
    atomicAdd(&gcnt[g], 1);
}

__global__ void goff_kernel(const int* __restrict__ gcnt, int* __restrict__ goff) {
    if (threadIdx.x == 0) {
        int acc = 0;
        for (int g = 0; g < NG; g++) { goff[g] = acc; acc += gcnt[g]; }
        goff[NG] = acc;
    }
}

// ======================= dtype-normalizing prep kernels ======================
// x (runtime dtype) -> bf16 bits
__global__ void cast_kernel(const void* __restrict__ x, short* __restrict__ xb,
                            const int* __restrict__ flags, int total) {
    int i = blockIdx.x * 256 + threadIdx.x;
    if (i >= total) return;
    xb[i] = f2bfbits(ldf(x, i, flags[1]));
}

// W [256x256] row-major -> fragment-linear B for mfma_f32_16x16x32_bf16:
// Bf[((kt*16 + ctile)*64 + lane)*8 + j] = W[kt*32 + (lane>>4)*8 + j][ctile*16 + (lane&15)]
__global__ void repack_kernel(const void* __restrict__ W, short* __restrict__ Bf,
                              const int* __restrict__ flags) {
    int i = blockIdx.x * 256 + threadIdx.x;  // 65536
    int j = i & 7, lane = (i >> 3) & 63, tile = i >> 9;
    int kt = tile >> 4, ctg = tile & 15;
    int k = kt * 32 + (lane >> 4) * 8 + j;
    int n = ctg * 16 + (lane & 15);
    Bf[i] = f2bfbits(ldf(W, k * NF + n, flags[1]));
}

// ======================= MFMA GEMM: C[M,256] = A[M,256] @ B[256,256] =========
// A: row-major bf16 bits (rows padded to MPAD). Bf: fragment-linear bf16 bits.
// Block: 4 waves; block tile 64 rows x 256 cols; wave tile 64x64 (4x4 MFMA tiles).
__global__ __launch_bounds__(256) void gemm_mfma(const short* __restrict__ A,
                                                 const short* __restrict__ Bf,
                                                 bf16* __restrict__ C, int M) {
    int wave = threadIdx.x >> 6;
    int lane = threadIdx.x & 63;
    int am = lane & 15, aq = lane >> 4;
    int row0 = blockIdx.x * 64;
    floatx4 acc[4][4];
    #pragma unroll
    for (int i = 0; i < 4; i++)
        #pragma unroll
        for (int j = 0; j < 4; j++) acc[i][j] = (floatx4){0.f, 0.f, 0.f, 0.f};
    for (int kt = 0; kt < 8; kt++) {
        short8 a[4], b[4];
        #pragma unroll
        for (int rt = 0; rt < 4; rt++)
            a[rt] = *(const short8*)&A[(row0 + rt * 16 + am) * NF + kt * 32 + aq * 8];
        #pragma unroll
        for (int ct = 0; ct < 4; ct++)
            b[ct] = *(const short8*)&Bf[((kt * 16 + wave * 4 + ct) * 64 + lane) * 8];
        #pragma unroll
        for (int rt = 0; rt < 4; rt++)
            #pragma unroll
            for (int ct = 0; ct < 4; ct++)
                acc[rt][ct] = __builtin_amdgcn_mfma_f32_16x16x32_bf16(a[rt], b[ct], acc[rt][ct], 0, 0, 0);
    }
    // C/D layout: col = lane&15, row = (lane>>4)*4 + reg   [m89-verified]
    int rbase = (lane >> 4) * 4;
    int cbase = wave * 64 + (lane & 15);
    #pragma unroll
    for (int rt = 0; rt < 4; rt++) {
        #pragma unroll
        for (int r = 0; r < 4; r++) {
            int row = row0 + rt * 16 + rbase + r;
            if (row < M) {
                #pragma unroll
                for (int ct = 0; ct < 4; ct++)
                    C[row * NF + cbase + ct * 16] = __float2bfloat16(acc[rt][ct][r]);
            }
        }
    }
}

// ---- per-node attention logits ---------------------------------------------
__global__ void att_kernel(const bf16* __restrict__ h, const void* __restrict__ att_s,
                           const void* __restrict__ att_d,
                           float* __restrict__ a_src, float* __restrict__ a_dst,
                           const int* __restrict__ flags) {
    int isbf = flags[1];
    int n = blockIdx.x;
    int t = threadIdx.x;
    float hv = __bfloat162float(h[n * NF + t]);
    float vs = hv * ldf(att_s, t, isbf);
    float vd = hv * ldf(att_d, t, isbf);
    #pragma unroll
    for (int off = 32; off > 0; off >>= 1) {
        vs += __shfl_down(vs, off, 64);
        vd += __shfl_down(vd, off, 64);
    }
    if ((t & 63) == 0) {
        a_src[n * NH + (t >> 6)] = vs;
        a_dst[n * NH + (t >> 6)] = vd;
    }
}

__device__ inline float leaky_clamp(float v) {
    v = v > 0.f ? v : 0.2f * v;
    return fminf(fmaxf(v, -30.f), 30.f);
}

// ---- fused per-dst softmax + aggregate + bias + ELU + residual -------------
// one block per dst; alphas computed lane-parallel into LDS per 64-edge chunk
__global__ void agg_csr_kernel(const int* __restrict__ rowptr, const int* __restrict__ srcs,
                               const float* __restrict__ asrc, const float* __restrict__ adst,
                               const bf16* __restrict__ h, const void* __restrict__ bias,
                               const void* __restrict__ resid, float* __restrict__ agg,
                               const int* __restrict__ flags, int residFollows) {
    int d = blockIdx.x;
    int t = threadIdx.x;        // 0..255 (one feature column each)
    int hh = t >> 6;            // head = wave id
    int lane = t & 63;
    int isbf = flags[1];
    int rIsBf = residFollows ? isbf : 1;
    int beg = rowptr[d], end = rowptr[d + 1];
    float ad = adst[d * NH + hh];
    __shared__ float sden[NH];
    // phase 1: softmax denominator per head (wave hh handles head hh)
    float part = 0.f;
    for (int k = beg + lane; k < end; k += 64)
        part += expf(leaky_clamp(asrc[srcs[k] * NH + hh] + ad));
    #pragma unroll
    for (int off = 32; off > 0; off >>= 1) part += __shfl_down(part, off, 64);
    if (lane == 0) sden[hh] = part;
    __syncthreads();
    float inv = 1.f / fmaxf(sden[hh], 1e-30f);
    // phase 2: chunked lane-parallel alpha + broadcast gather
    __shared__ int sSrc[64];
    __shared__ float sAl[NH][64];
    float acc = 0.f;
    for (int cb = beg; cb < end; cb += 64) {
        int nk = min(64, end - cb);
        if (lane < nk) {
            int s = srcs[cb + lane];
            sSrc[lane] = s;  // all 4 waves write identical values — benign
            sAl[hh][lane] = expf(leaky_clamp(asrc[s * NH + hh] + ad)) * inv;
        }
        __syncthreads();
        for (int e = 0; e < nk; e++)
            acc += sAl[hh][e] * __bfloat162float(h[sSrc[e] * NF + t]);
        __syncthreads();
    }
    // epilogue: + bias, ELU, + residual
    float v = acc + ldf(bias, t, isbf);
    v = v > 0.f ? v : (expf(v) - 1.0f);
    agg[d * NF + t] = v + ldf(resid, d * NF + t, rIsBf);
}

__global__ void bn_stats_kernel(const float* __restrict__ x, float* __restrict__ bsum,
                                float* __restrict__ bsumsq) {
    int f = threadIdx.x;
    float s = 0.f, sq = 0.f;
    for (int r = blockIdx.x; r < NNODES; r += gridDim.x) {
        float v = x[r * NF + f];
        s += v;
        sq += v * v;
    }
    atomicAdd(&bsum[f], s);
    atomicAdd(&bsumsq[f], sq);
}

template <typename OT>
__global__ void bn_norm_kernel(const float* __restrict__ x, const float* __restrict__ bsum,
                               const float* __restrict__ bsumsq,
                               const void* __restrict__ gamma, const void* __restrict__ beta,
                               OT* __restrict__ out, int total, const int* __restrict__ flags) {
    int i = blockIdx.x * blockDim.x + threadIdx.x;
    if (i >= total) return;
    int isbf = flags[1];
    const float invN = 1.0f / (float)NNODES;
    int f = i & (NF - 1);
    float mu = bsum[f] * invN;
    float var = fmaxf(bsumsq[f] * invN - mu * mu, 0.f);
    float v = (x[i] - mu) * rsqrtf(var + 1e-5f);
    stOut(out[i], ldf(gamma, f, isbf) * v + ldf(beta, f, isbf));
}

// ---- pooling: contiguous node slices per graph (batch is sorted) -----------
__global__ void pool2_kernel(const float* __restrict__ x, const int* __restrict__ goff,
                             float* __restrict__ pooled) {
    int g = blockIdx.x >> 3, c = blockIdx.x & 7, t = threadIdx.x;
    int beg = goff[g], end = goff[g + 1];
    int len = end - beg;
    if (len <= 0) return;
    int chunk = (len + 7) >> 3;
    int s0 = beg + c * chunk;
    int s1 = min(s0 + chunk, end);
    if (s0 >= s1) return;
    float acc = 0.f;
    for (int n = s0; n < s1; n++) acc += x[n * NF + t];
    atomicAdd(&pooled[g * NF + t], acc);
}

__global__ void head_kernel(const float* __restrict__ pooled, const int* __restrict__ gcnt,
                            const void* __restrict__ fc1w, const void* __restrict__ fc1b,
                            const void* __restrict__ fc2w, const void* __restrict__ fc2b,
                            void* __restrict__ out, const int* __restrict__ flags) {
    int g = blockIdx.x;
    int t = threadIdx.x;  // 64
    int isbf = flags[1];
    __shared__ float p[NF];
    __shared__ float z[64];
    __shared__ float logits[NCLS];
    __shared__ float lse;
    float c = fmaxf((float)gcnt[g], 1.f);
    float invc = 1.f / c;
    for (int i = t; i < NF; i += 64) p[i] = pooled[g * NF + i] * invc;
    __syncthreads();
    float acc = ldf(fc1b, t, isbf);
    for (int k = 0; k < NF; k++) acc += p[k] * ldf(fc1w, k * 64 + t, isbf);
    z[t] = acc > 0.f ? acc : 0.f;
    __syncthreads();
    if (t < NCLS) {
        float a2 = ldf(fc2b, t, isbf);
        for (int k = 0; k < 64; k++) a2 += z[k] * ldf(fc2w, k * NCLS + t, isbf);
        logits[t] = a2;
    }
    __syncthreads();
    if (t == 0) {
        float mx = logits[0];
        for (int j = 1; j < NCLS; j++) mx = fmaxf(mx, logits[j]);
        float se = 0.f;
        for (int j = 0; j < NCLS; j++) se += expf(logits[j] - mx);
        lse = mx + logf(se);
    }
    __syncthreads();
    if (t < NCLS) stf(out, g * NCLS + t, logits[t] - lse, isbf);
}

extern "C" void kernel_launch(void* const* d_in, const int* in_sizes, int n_in,
                              void* d_out, int out_size, void* d_ws, size_t ws_size,
                              hipStream_t stream) {
    const void* x = d_in[0];
    const int* edge_index = (const int*)d_in[1];
    const int* batch = (const int*)d_in[2];
    const void* W1 = d_in[3];
    const void* att_src1 = d_in[4];
    const void* att_dst1 = d_in[5];
    const void* b1 = d_in[6];
    const void* gamma1 = d_in[7];
    const void* beta1 = d_in[8];
    const void* W2 = d_in[9];
    const void* att_src2 = d_in[10];
    const void* att_dst2 = d_in[11];
    const void* b2 = d_in[12];
    const void* gamma2 = d_in[13];
    const void* beta2 = d_in[14];
    const void* fc1w = d_in[15];
    const void* fc1b = d_in[16];
    const void* fc2w = d_in[17];
    const void* fc2b = d_in[18];

    const int E = in_sizes[1] / 2;     // 400000
    const int ET = E + NNODES;         // + self-loops
    const int NE = NNODES * NF;
    const int NNH = NNODES * NH;
    const int NB = (NNODES + 255) / 256;
    const int NB1 = (NNODES + 1 + 255) / 256;

    // ---- workspace layout ----
    float* ws = (float*)d_ws;
    float* agg = ws;                       // N*256 fp32 (also aliases xb during GEMM1)
    float* asrc = agg + NE;                // N*4 (also aliases scan scratch)
    float* adst = asrc + NNH;              // N*4
    int* flags = (int*)(adst + NNH);       // 16
    bf16* hb = (bf16*)(flags + 16);        // N*256 bf16
    bf16* l1ob = hb + NE;                  // MPAD*256 bf16 (padded for gemm A reads)
    int* rowptr = (int*)(l1ob + (size_t)MPAD * NF);  // N+1 (+pad)
    int* srcs = rowptr + NNODES + 16;      // ET
    int* goff = srcs + ET + 16;            // NG+1
    // zero region (single memset): deg, cursor, gcnt, pooled, bnstat
    int* deg = goff + NG + 1 + 14;
    int* cursor = deg + NNODES;
    int* gcnt = cursor + NNODES;
    float* pooled = (float*)(gcnt + NG);   // 64*256
    float* bnstat = pooled + NG * NF;      // 4*256
    size_t zero_bytes = (size_t)(2 * NNODES + NG) * 4 + (size_t)(NG * NF + 4 * NF) * 4;
    short* Bf1 = (short*)(bnstat + 4 * NF);  // 65536 (outside zero region)
    short* Bf2 = Bf1 + NF * NF;              // 65536
    // scan scratch aliased onto asrc/adst (overwritten later by att_kernel)
    int* eprefix = (int*)asrc;
    int* bsums = eprefix + NNODES + 16;
    int* boffs = bsums + 256;
    // xb aliased onto agg (agg first written by agg_csr, after GEMM1 consumed xb)
    short* xb = (short*)agg;               // MPAD*256 bf16 bits (25.6MB < 51.2MB)

    float* bnsum1 = bnstat;
    float* bnsq1 = bnstat + NF;
    float* bnsum2 = bnstat + 2 * NF;
    float* bnsq2 = bnstat + 3 * NF;

    detect_kernel<<<1, 256, 0, stream>>>(edge_index, (const unsigned*)W1, flags);
    hipMemsetAsync(deg, 0, zero_bytes, stream);

    // ---- dtype-normalize inputs for MFMA ----
    cast_kernel<<<(NE + 255) / 256, 256, 0, stream>>>(x, xb, flags, NE);
    repack_kernel<<<NF * NF / 256, 256, 0, stream>>>(W1, Bf1, flags);
    repack_kernel<<<NF * NF / 256, 256, 0, stream>>>(W2, Bf2, flags);

    // ---- CSR build + graph boundaries (reused by both layers) ----
    deg_kernel<<<(ET + 255) / 256, 256, 0, stream>>>(edge_index, deg, E, ET, flags);
    scan1_kernel<<<NB, 256, 0, stream>>>(deg, eprefix, bsums, NNODES);
    scan2_kernel<<<1, 256, 0, stream>>>(bsums, boffs, NB);
    scan3_kernel<<<NB1, 256, 0, stream>>>(eprefix, boffs, rowptr, NNODES, ET);
    scatter_kernel<<<(ET + 255) / 256, 256, 0, stream>>>(edge_index, rowptr, cursor, srcs, E, ET, flags);
    gcnt_kernel<<<NB, 256, 0, stream>>>(batch, gcnt, flags);
    goff_kernel<<<1, 64, 0, stream>>>(gcnt, goff);

    // ================= layer 1 =================
    gemm_mfma<<<MPAD / 64, 256, 0, stream>>>(xb, Bf1, hb, NNODES);
    att_kernel<<<NNODES, 256, 0, stream>>>(hb, att_src1, att_dst1, asrc, adst, flags);
    agg_csr_kernel<<<NNODES, 256, 0, stream>>>(rowptr, srcs, asrc, adst, hb, b1, x, agg, flags, 1);
    bn_stats_kernel<<<512, 256, 0, stream>>>(agg, bnsum1, bnsq1);
    bn_norm_kernel<bf16><<<(NE + 255) / 256, 256, 0, stream>>>(agg, bnsum1, bnsq1, gamma1, beta1, l1ob, NE, flags);

    // ================= layer 2 =================
    gemm_mfma<<<MPAD / 64, 256, 0, stream>>>((const short*)l1ob, Bf2, hb, NNODES);
    att_kernel<<<NNODES, 256, 0, stream>>>(hb, att_src2, att_dst2, asrc, adst, flags);
    agg_csr_kernel<<<NNODES, 256, 0, stream>>>(rowptr, srcs, asrc, adst, hb, b2, l1ob, agg, flags, 0);
    bn_stats_kernel<<<512, 256, 0, stream>>>(agg, bnsum2, bnsq2);
    bn_norm_kernel<float><<<(NE + 255) / 256, 256, 0, stream>>>(agg, bnsum2, bnsq2, gamma2, beta2, agg, NE, flags);

    // ================= pool + head =================
    pool2_kernel<<<NG * 8, 256, 0, stream>>>(agg, goff, pooled);
    head_kernel<<<NG, 64, 0, stream>>>(pooled, gcnt, fc1w, fc1b, fc2w, fc2b, d_out, flags);
}

// Round 6
// 728.101 us; speedup vs baseline: 3.0306x; 1.3072x over previous
//
#include <hip/hip_runtime.h>
#include <hip/hip_bf16.h>

#define NNODES 50000
#define NF 256
#define NH 4
#define NG 64
#define NCLS 10
#define MPAD 50048  // NNODES rounded up to multiple of 64 (gemm row padding)

typedef __hip_bfloat16 bf16;
typedef __attribute__((ext_vector_type(8))) short short8;   // 8 bf16 = 4 VGPRs
typedef __attribute__((ext_vector_type(4))) float floatx4;  // MFMA accumulator

// flags[0] = indices are int64 ; flags[1] = floats are bf16
__device__ inline float ldf(const void* p, int i, int isbf) {
    return isbf ? __bfloat162float(((const bf16*)p)[i]) : ((const float*)p)[i];
}
__device__ inline void stf(void* p, int i, float v, int isbf) {
    if (isbf) ((bf16*)p)[i] = __float2bfloat16(v);
    else ((float*)p)[i] = v;
}
__device__ inline short f2bfbits(float v) {
    bf16 b = __float2bfloat16(v);
    return *reinterpret_cast<short*>(&b);
}
__device__ inline void stOut(float& d, float v) { d = v; }
__device__ inline void stOut(bf16& d, float v) { d = __float2bfloat16(v); }
__device__ inline int clampN(int v) { return ((unsigned)v < (unsigned)NNODES) ? v : 0; }
__device__ inline int clampG(int v) { return ((unsigned)v < (unsigned)NG) ? v : 0; }

__global__ void detect_kernel(const int* __restrict__ ei, const unsigned* __restrict__ w1,
                              int* __restrict__ flags) {
    __shared__ int nzOdd, insane;
    if (threadIdx.x == 0) { nzOdd = 0; insane = 0; }
    __syncthreads();
    if (ei[2 * threadIdx.x + 1] != 0) atomicAdd(&nzOdd, 1);
    unsigned lo = w1[threadIdx.x] & 0xFFFFu;
    unsigned ex = (lo >> 7) & 0xFFu;
    bool sane = ((lo & 0x7FFFu) == 0u) || (ex >= 90u && ex <= 133u);
    if (!sane) atomicAdd(&insane, 1);
    __syncthreads();
    if (threadIdx.x == 0) {
        flags[0] = (nzOdd == 0) ? 1 : 0;
        flags[1] = (insane == 0) ? 1 : 0;
    }
}

__device__ inline void edge_sd(const int* __restrict__ ei, int e, int E, int is64,
                               int& s_, int& d_) {
    if (e < E) {
        if (is64) { s_ = ei[2 * e]; d_ = ei[2 * E + 2 * e]; }
        else      { s_ = ei[e];     d_ = ei[E + e]; }
    } else {
        s_ = d_ = e - E;  // self-loop
    }
    s_ = clampN(s_);
    d_ = clampN(d_);
}

// ======================= CSR build (once, reused both layers) ================
__global__ void deg_kernel(const int* __restrict__ ei, int* __restrict__ deg,
                           int E, int ET, const int* __restrict__ flags) {
    int e = blockIdx.x * 256 + threadIdx.x;
    if (e >= ET) return;
    int s_, d_;
    edge_sd(ei, e, E, flags[0], s_, d_);
    atomicAdd(&deg[d_], 1);
}

__global__ void scan1_kernel(const int* __restrict__ deg, int* __restrict__ eprefix,
                             int* __restrict__ bsums, int n) {
    __shared__ int sc[256];
    int t = threadIdx.x, i = blockIdx.x * 256 + t;
    int val = (i < n) ? deg[i] : 0;
    sc[t] = val;
    __syncthreads();
    for (int off = 1; off < 256; off <<= 1) {
        int tmp = (t >= off) ? sc[t - off] : 0;
        __syncthreads();
        sc[t] += tmp;
        __syncthreads();
    }
    if (i < n) eprefix[i] = sc[t] - val;
    if (t == 255) bsums[blockIdx.x] = sc[255];
}

__global__ void scan2_kernel(const int* __restrict__ bsums, int* __restrict__ boffs, int nb) {
    __shared__ int sc[256];
    int t = threadIdx.x;
    int val = (t < nb) ? bsums[t] : 0;
    sc[t] = val;
    __syncthreads();
    for (int off = 1; off < 256; off <<= 1) {
        int tmp = (t >= off) ? sc[t - off] : 0;
        __syncthreads();
        sc[t] += tmp;
        __syncthreads();
    }
    if (t < nb) boffs[t] = sc[t] - val;
}

__global__ void scan3_kernel(const int* __restrict__ eprefix, const int* __restrict__ boffs,
                             int* __restrict__ rowptr, int n, int ET) {
    int i = blockIdx.x * 256 + threadIdx.x;
    if (i < n) rowptr[i] = eprefix[i] + boffs[blockIdx.x];
    if (i == n) rowptr[n] = ET;
}

__global__ void scatter_kernel(const int* __restrict__ ei, const int* __restrict__ rowptr,
                               int* __restrict__ cursor, int* __restrict__ srcs,
                               int E, int ET, const int* __restrict__ flags) {
    int e = blockIdx.x * 256 + threadIdx.x;
    if (e >= ET) return;
    int s_, d_;
    edge_sd(ei, e, E, flags[0], s_, d_);
    int pos = atomicAdd(&cursor[d_], 1);
    srcs[rowptr[d_] + pos] = s_;
}

// ========== graph boundaries via binary search (batch is sorted, no atomics) =
__global__ void goff_bs_kernel(const int* __restrict__ bt, int* __restrict__ goff,
                               int* __restrict__ gcnt, const int* __restrict__ flags) {
    int is64 = flags[0];
    int t = threadIdx.x;  // 0..127
    if (t <= NG) {
        int lo = 0, hi = NNODES;
        while (lo < hi) {  // first n with batch[n] >= t
            int mid = (lo + hi) >> 1;
            int b = clampG(is64 ? bt[2 * mid] : bt[mid]);
            if (b < t) lo = mid + 1; else hi = mid;
        }
        goff[t] = lo;
    }
    __syncthreads();
    if (t < NG) gcnt[t] = goff[t + 1] - goff[t];
}

// ======================= dtype-normalizing prep kernels ======================
__global__ void cast_kernel(const void* __restrict__ x, short* __restrict__ xb,
                            const int* __restrict__ flags, int total) {
    int i = blockIdx.x * 256 + threadIdx.x;
    if (i >= total) return;
    xb[i] = f2bfbits(ldf(x, i, flags[1]));
}

// W [256x256] row-major -> fragment-linear B for mfma_f32_16x16x32_bf16:
// Bf[((kt*16 + ctile)*64 + lane)*8 + j] = W[kt*32 + (lane>>4)*8 + j][ctile*16 + (lane&15)]
__global__ void repack_kernel(const void* __restrict__ W, short* __restrict__ Bf,
                              const int* __restrict__ flags) {
    int i = blockIdx.x * 256 + threadIdx.x;  // 65536
    int j = i & 7, lane = (i >> 3) & 63, tile = i >> 9;
    int kt = tile >> 4, ctg = tile & 15;
    int k = kt * 32 + (lane >> 4) * 8 + j;
    int n = ctg * 16 + (lane & 15);
    Bf[i] = f2bfbits(ldf(W, k * NF + n, flags[1]));
}

// ======================= MFMA GEMM: C[M,256] = A[M,256] @ B[256,256] =========
__global__ __launch_bounds__(256) void gemm_mfma(const short* __restrict__ A,
                                                 const short* __restrict__ Bf,
                                                 bf16* __restrict__ C, int M) {
    int wave = threadIdx.x >> 6;
    int lane = threadIdx.x & 63;
    int am = lane & 15, aq = lane >> 4;
    int row0 = blockIdx.x * 64;
    floatx4 acc[4][4];
    #pragma unroll
    for (int i = 0; i < 4; i++)
        #pragma unroll
        for (int j = 0; j < 4; j++) acc[i][j] = (floatx4){0.f, 0.f, 0.f, 0.f};
    for (int kt = 0; kt < 8; kt++) {
        short8 a[4], b[4];
        #pragma unroll
        for (int rt = 0; rt < 4; rt++)
            a[rt] = *(const short8*)&A[(row0 + rt * 16 + am) * NF + kt * 32 + aq * 8];
        #pragma unroll
        for (int ct = 0; ct < 4; ct++)
            b[ct] = *(const short8*)&Bf[((kt * 16 + wave * 4 + ct) * 64 + lane) * 8];
        #pragma unroll
        for (int rt = 0; rt < 4; rt++)
            #pragma unroll
            for (int ct = 0; ct < 4; ct++)
                acc[rt][ct] = __builtin_amdgcn_mfma_f32_16x16x32_bf16(a[rt], b[ct], acc[rt][ct], 0, 0, 0);
    }
    int rbase = (lane >> 4) * 4;
    int cbase = wave * 64 + (lane & 15);
    #pragma unroll
    for (int rt = 0; rt < 4; rt++) {
        #pragma unroll
        for (int r = 0; r < 4; r++) {
            int row = row0 + rt * 16 + rbase + r;
            if (row < M) {
                #pragma unroll
                for (int ct = 0; ct < 4; ct++)
                    C[row * NF + cbase + ct * 16] = __float2bfloat16(acc[rt][ct][r]);
            }
        }
    }
}

// ---- per-node attention logits ---------------------------------------------
__global__ void att_kernel(const bf16* __restrict__ h, const void* __restrict__ att_s,
                           const void* __restrict__ att_d,
                           float* __restrict__ a_src, float* __restrict__ a_dst,
                           const int* __restrict__ flags) {
    int isbf = flags[1];
    int n = blockIdx.x;
    int t = threadIdx.x;
    float hv = __bfloat162float(h[n * NF + t]);
    float vs = hv * ldf(att_s, t, isbf);
    float vd = hv * ldf(att_d, t, isbf);
    #pragma unroll
    for (int off = 32; off > 0; off >>= 1) {
        vs += __shfl_down(vs, off, 64);
        vd += __shfl_down(vd, off, 64);
    }
    if ((t & 63) == 0) {
        a_src[n * NH + (t >> 6)] = vs;
        a_dst[n * NH + (t >> 6)] = vd;
    }
}

__device__ inline float leaky_clamp(float v) {
    v = v > 0.f ? v : 0.2f * v;
    return fminf(fmaxf(v, -30.f), 30.f);
}

// ---- fused per-dst softmax + aggregate + bias + ELU + residual -------------
__global__ void agg_csr_kernel(const int* __restrict__ rowptr, const int* __restrict__ srcs,
                               const float* __restrict__ asrc, const float* __restrict__ adst,
                               const bf16* __restrict__ h, const void* __restrict__ bias,
                               const void* __restrict__ resid, float* __restrict__ agg,
                               const int* __restrict__ flags, int residFollows) {
    int d = blockIdx.x;
    int t = threadIdx.x;        // 0..255 (one feature column each)
    int hh = t >> 6;            // head = wave id
    int lane = t & 63;
    int isbf = flags[1];
    int rIsBf = residFollows ? isbf : 1;
    int beg = rowptr[d], end = rowptr[d + 1];
    float ad = adst[d * NH + hh];
    __shared__ float sden[NH];
    float part = 0.f;
    for (int k = beg + lane; k < end; k += 64)
        part += expf(leaky_clamp(asrc[srcs[k] * NH + hh] + ad));
    #pragma unroll
    for (int off = 32; off > 0; off >>= 1) part += __shfl_down(part, off, 64);
    if (lane == 0) sden[hh] = part;
    __syncthreads();
    float inv = 1.f / fmaxf(sden[hh], 1e-30f);
    __shared__ int sSrc[64];
    __shared__ float sAl[NH][64];
    float acc = 0.f;
    for (int cb = beg; cb < end; cb += 64) {
        int nk = min(64, end - cb);
        if (lane < nk) {
            int s = srcs[cb + lane];
            sSrc[lane] = s;
            sAl[hh][lane] = expf(leaky_clamp(asrc[s * NH + hh] + ad)) * inv;
        }
        __syncthreads();
        for (int e = 0; e < nk; e++)
            acc += sAl[hh][e] * __bfloat162float(h[sSrc[e] * NF + t]);
        __syncthreads();
    }
    float v = acc + ldf(bias, t, isbf);
    v = v > 0.f ? v : (expf(v) - 1.0f);
    agg[d * NF + t] = v + ldf(resid, d * NF + t, rIsBf);
}

__global__ void bn_stats_kernel(const float* __restrict__ x, float* __restrict__ bsum,
                                float* __restrict__ bsumsq) {
    int f = threadIdx.x;
    float s = 0.f, sq = 0.f;
    for (int r = blockIdx.x; r < NNODES; r += gridDim.x) {
        float v = x[r * NF + f];
        s += v;
        sq += v * v;
    }
    atomicAdd(&bsum[f], s);
    atomicAdd(&bsumsq[f], sq);
}

template <typename OT>
__global__ void bn_norm_kernel(const float* __restrict__ x, const float* __restrict__ bsum,
                               const float* __restrict__ bsumsq,
                               const void* __restrict__ gamma, const void* __restrict__ beta,
                               OT* __restrict__ out, int total, const int* __restrict__ flags) {
    int i = blockIdx.x * blockDim.x + threadIdx.x;
    if (i >= total) return;
    int isbf = flags[1];
    const float invN = 1.0f / (float)NNODES;
    int f = i & (NF - 1);
    float mu = bsum[f] * invN;
    float var = fmaxf(bsumsq[f] * invN - mu * mu, 0.f);
    float v = (x[i] - mu) * rsqrtf(var + 1e-5f);
    stOut(out[i], ldf(gamma, f, isbf) * v + ldf(beta, f, isbf));
}

// ---- pooling: contiguous node slices per graph (batch is sorted) -----------
__global__ void pool2_kernel(const float* __restrict__ x, const int* __restrict__ goff,
                             float* __restrict__ pooled) {
    int g = blockIdx.x >> 3, c = blockIdx.x & 7, t = threadIdx.x;
    int beg = goff[g], end = goff[g + 1];
    int len = end - beg;
    if (len <= 0) return;
    int chunk = (len + 7) >> 3;
    int s0 = beg + c * chunk;
    int s1 = min(s0 + chunk, end);
    if (s0 >= s1) return;
    float acc = 0.f;
    for (int n = s0; n < s1; n++) acc += x[n * NF + t];
    atomicAdd(&pooled[g * NF + t], acc);
}

__global__ void head_kernel(const float* __restrict__ pooled, const int* __restrict__ gcnt,
                            const void* __restrict__ fc1w, const void* __restrict__ fc1b,
                            const void* __restrict__ fc2w, const void* __restrict__ fc2b,
                            void* __restrict__ out, const int* __restrict__ flags) {
    int g = blockIdx.x;
    int t = threadIdx.x;  // 64
    int isbf = flags[1];
    __shared__ float p[NF];
    __shared__ float z[64];
    __shared__ float logits[NCLS];
    __shared__ float lse;
    float c = fmaxf((float)gcnt[g], 1.f);
    float invc = 1.f / c;
    for (int i = t; i < NF; i += 64) p[i] = pooled[g * NF + i] * invc;
    __syncthreads();
    float acc = ldf(fc1b, t, isbf);
    for (int k = 0; k < NF; k++) acc += p[k] * ldf(fc1w, k * 64 + t, isbf);
    z[t] = acc > 0.f ? acc : 0.f;
    __syncthreads();
    if (t < NCLS) {
        float a2 = ldf(fc2b, t, isbf);
        for (int k = 0; k < 64; k++) a2 += z[k] * ldf(fc2w, k * NCLS + t, isbf);
        logits[t] = a2;
    }
    __syncthreads();
    if (t == 0) {
        float mx = logits[0];
        for (int j = 1; j < NCLS; j++) mx = fmaxf(mx, logits[j]);
        float se = 0.f;
        for (int j = 0; j < NCLS; j++) se += expf(logits[j] - mx);
        lse = mx + logf(se);
    }
    __syncthreads();
    if (t < NCLS) stf(out, g * NCLS + t, logits[t] - lse, isbf);
}

extern "C" void kernel_launch(void* const* d_in, const int* in_sizes, int n_in,
                              void* d_out, int out_size, void* d_ws, size_t ws_size,
                              hipStream_t stream) {
    const void* x = d_in[0];
    const int* edge_index = (const int*)d_in[1];
    const int* batch = (const int*)d_in[2];
    const void* W1 = d_in[3];
    const void* att_src1 = d_in[4];
    const void* att_dst1 = d_in[5];
    const void* b1 = d_in[6];
    const void* gamma1 = d_in[7];
    const void* beta1 = d_in[8];
    const void* W2 = d_in[9];
    const void* att_src2 = d_in[10];
    const void* att_dst2 = d_in[11];
    const void* b2 = d_in[12];
    const void* gamma2 = d_in[13];
    const void* beta2 = d_in[14];
    const void* fc1w = d_in[15];
    const void* fc1b = d_in[16];
    const void* fc2w = d_in[17];
    const void* fc2b = d_in[18];

    const int E = in_sizes[1] / 2;     // 400000
    const int ET = E + NNODES;         // + self-loops
    const int NE = NNODES * NF;
    const int NNH = NNODES * NH;
    const int NB = (NNODES + 255) / 256;
    const int NB1 = (NNODES + 1 + 255) / 256;

    // ---- workspace layout ----
    float* ws = (float*)d_ws;
    float* agg = ws;                       // N*256 fp32 (also aliases xb during GEMM1)
    float* asrc = agg + NE;                // N*4 (also aliases scan scratch)
    float* adst = asrc + NNH;              // N*4
    int* flags = (int*)(adst + NNH);       // 16
    bf16* hb = (bf16*)(flags + 16);        // N*256 bf16
    bf16* l1ob = hb + NE;                  // MPAD*256 bf16 (padded for gemm A reads)
    int* rowptr = (int*)(l1ob + (size_t)MPAD * NF);  // N+1 (+pad)
    int* srcs = rowptr + NNODES + 16;      // ET
    int* goff = srcs + ET + 16;            // NG+1
    // zero region (single memset): deg, cursor, gcnt, pooled, bnstat
    int* deg = goff + NG + 1 + 14;
    int* cursor = deg + NNODES;
    int* gcnt = cursor + NNODES;
    float* pooled = (float*)(gcnt + NG);   // 64*256
    float* bnstat = pooled + NG * NF;      // 4*256
    size_t zero_bytes = (size_t)(2 * NNODES + NG) * 4 + (size_t)(NG * NF + 4 * NF) * 4;
    short* Bf1 = (short*)(bnstat + 4 * NF);  // 65536 (outside zero region)
    short* Bf2 = Bf1 + NF * NF;              // 65536
    // scan scratch aliased onto asrc/adst (overwritten later by att_kernel)
    int* eprefix = (int*)asrc;
    int* bsums = eprefix + NNODES + 16;
    int* boffs = bsums + 256;
    // xb aliased onto agg (agg first written by agg_csr, after GEMM1 consumed xb)
    short* xb = (short*)agg;               // MPAD*256 bf16 bits (25.6MB < 51.2MB)

    float* bnsum1 = bnstat;
    float* bnsq1 = bnstat + NF;
    float* bnsum2 = bnstat + 2 * NF;
    float* bnsq2 = bnstat + 3 * NF;

    detect_kernel<<<1, 256, 0, stream>>>(edge_index, (const unsigned*)W1, flags);
    hipMemsetAsync(deg, 0, zero_bytes, stream);

    // ---- dtype-normalize inputs for MFMA ----
    cast_kernel<<<(NE + 255) / 256, 256, 0, stream>>>(x, xb, flags, NE);
    repack_kernel<<<NF * NF / 256, 256, 0, stream>>>(W1, Bf1, flags);
    repack_kernel<<<NF * NF / 256, 256, 0, stream>>>(W2, Bf2, flags);

    // ---- CSR build + graph boundaries (reused by both layers) ----
    deg_kernel<<<(ET + 255) / 256, 256, 0, stream>>>(edge_index, deg, E, ET, flags);
    scan1_kernel<<<NB, 256, 0, stream>>>(deg, eprefix, bsums, NNODES);
    scan2_kernel<<<1, 256, 0, stream>>>(bsums, boffs, NB);
    scan3_kernel<<<NB1, 256, 0, stream>>>(eprefix, boffs, rowptr, NNODES, ET);
    scatter_kernel<<<(ET + 255) / 256, 256, 0, stream>>>(edge_index, rowptr, cursor, srcs, E, ET, flags);
    goff_bs_kernel<<<1, 128, 0, stream>>>(batch, goff, gcnt, flags);

    // ================= layer 1 =================
    gemm_mfma<<<MPAD / 64, 256, 0, stream>>>(xb, Bf1, hb, NNODES);
    att_kernel<<<NNODES, 256, 0, stream>>>(hb, att_src1, att_dst1, asrc, adst, flags);
    agg_csr_kernel<<<NNODES, 256, 0, stream>>>(rowptr, srcs, asrc, adst, hb, b1, x, agg, flags, 1);
    bn_stats_kernel<<<512, 256, 0, stream>>>(agg, bnsum1, bnsq1);
    bn_norm_kernel<bf16><<<(NE + 255) / 256, 256, 0, stream>>>(agg, bnsum1, bnsq1, gamma1, beta1, l1ob, NE, flags);

    // ================= layer 2 =================
    gemm_mfma<<<MPAD / 64, 256, 0, stream>>>((const short*)l1ob, Bf2, hb, NNODES);
    att_kernel<<<NNODES, 256, 0, stream>>>(hb, att_src2, att_dst2, asrc, adst, flags);
    agg_csr_kernel<<<NNODES, 256, 0, stream>>>(rowptr, srcs, asrc, adst, hb, b2, l1ob, agg, flags, 0);
    bn_stats_kernel<<<512, 256, 0, stream>>>(agg, bnsum2, bnsq2);
    bn_norm_kernel<float><<<(NE + 255) / 256, 256, 0, stream>>>(agg, bnsum2, bnsq2, gamma2, beta2, agg, NE, flags);

    // ================= pool + head =================
    pool2_kernel<<<NG * 8, 256, 0, stream>>>(agg, goff, pooled);
    head_kernel<<<NG, 64, 0, stream>>>(pooled, gcnt, fc1w, fc1b, fc2w, fc2b, d_out, flags);
}

// Round 7
// 642.262 us; speedup vs baseline: 3.4356x; 1.1337x over previous
//
#include <hip/hip_runtime.h>
#include <hip/hip_bf16.h>

#define NNODES 50000
#define NF 256
#define NH 4
#define NG 64
#define NCLS 10
#define MPAD 50048  // NNODES rounded up to multiple of 64 (gemm row padding)

typedef __hip_bfloat16 bf16;
typedef __attribute__((ext_vector_type(8))) short short8;   // 8 bf16 = 4 VGPRs
typedef __attribute__((ext_vector_type(4))) float floatx4;  // MFMA accumulator

// flags[0] = indices are int64 ; flags[1] = floats are bf16
__device__ inline float ldf(const void* p, int i, int isbf) {
    return isbf ? __bfloat162float(((const bf16*)p)[i]) : ((const float*)p)[i];
}
// load 2 consecutive floats at even index i
__device__ inline float2 ld2f(const void* p, int i, int isbf) {
    if (isbf) {
        unsigned u = *(const unsigned*)((const short*)p + i);
        return make_float2(__uint_as_float(u << 16), __uint_as_float(u & 0xFFFF0000u));
    }
    return *(const float2*)((const float*)p + i);
}
__device__ inline void stf(void* p, int i, float v, int isbf) {
    if (isbf) ((bf16*)p)[i] = __float2bfloat16(v);
    else ((float*)p)[i] = v;
}
__device__ inline short f2bfbits(float v) {
    bf16 b = __float2bfloat16(v);
    return *reinterpret_cast<short*>(&b);
}
__device__ inline void stOut(float& d, float v) { d = v; }
__device__ inline void stOut(bf16& d, float v) { d = __float2bfloat16(v); }
__device__ inline int clampN(int v) { return ((unsigned)v < (unsigned)NNODES) ? v : 0; }
__device__ inline int clampG(int v) { return ((unsigned)v < (unsigned)NG) ? v : 0; }

__global__ void detect_kernel(const int* __restrict__ ei, const unsigned* __restrict__ w1,
                              int* __restrict__ flags) {
    __shared__ int nzOdd, insane;
    if (threadIdx.x == 0) { nzOdd = 0; insane = 0; }
    __syncthreads();
    if (ei[2 * threadIdx.x + 1] != 0) atomicAdd(&nzOdd, 1);
    unsigned lo = w1[threadIdx.x] & 0xFFFFu;
    unsigned ex = (lo >> 7) & 0xFFu;
    bool sane = ((lo & 0x7FFFu) == 0u) || (ex >= 90u && ex <= 133u);
    if (!sane) atomicAdd(&insane, 1);
    __syncthreads();
    if (threadIdx.x == 0) {
        flags[0] = (nzOdd == 0) ? 1 : 0;
        flags[1] = (insane == 0) ? 1 : 0;
    }
}

__device__ inline void edge_sd(const int* __restrict__ ei, int e, int E, int is64,
                               int& s_, int& d_) {
    if (e < E) {
        if (is64) { s_ = ei[2 * e]; d_ = ei[2 * E + 2 * e]; }
        else      { s_ = ei[e];     d_ = ei[E + e]; }
    } else {
        s_ = d_ = e - E;  // self-loop
    }
    s_ = clampN(s_);
    d_ = clampN(d_);
}

// ======================= CSR build (once, reused both layers) ================
__global__ void deg_kernel(const int* __restrict__ ei, int* __restrict__ deg,
                           int E, int ET, const int* __restrict__ flags) {
    int e = blockIdx.x * 256 + threadIdx.x;
    if (e >= ET) return;
    int s_, d_;
    edge_sd(ei, e, E, flags[0], s_, d_);
    atomicAdd(&deg[d_], 1);
}

__global__ void scan1_kernel(const int* __restrict__ deg, int* __restrict__ eprefix,
                             int* __restrict__ bsums, int n) {
    __shared__ int sc[256];
    int t = threadIdx.x, i = blockIdx.x * 256 + t;
    int val = (i < n) ? deg[i] : 0;
    sc[t] = val;
    __syncthreads();
    for (int off = 1; off < 256; off <<= 1) {
        int tmp = (t >= off) ? sc[t - off] : 0;
        __syncthreads();
        sc[t] += tmp;
        __syncthreads();
    }
    if (i < n) eprefix[i] = sc[t] - val;
    if (t == 255) bsums[blockIdx.x] = sc[255];
}

__global__ void scan2_kernel(const int* __restrict__ bsums, int* __restrict__ boffs, int nb) {
    __shared__ int sc[256];
    int t = threadIdx.x;
    int val = (t < nb) ? bsums[t] : 0;
    sc[t] = val;
    __syncthreads();
    for (int off = 1; off < 256; off <<= 1) {
        int tmp = (t >= off) ? sc[t - off] : 0;
        __syncthreads();
        sc[t] += tmp;
        __syncthreads();
    }
    if (t < nb) boffs[t] = sc[t] - val;
}

__global__ void scan3_kernel(const int* __restrict__ eprefix, const int* __restrict__ boffs,
                             int* __restrict__ rowptr, int n, int ET) {
    int i = blockIdx.x * 256 + threadIdx.x;
    if (i < n) rowptr[i] = eprefix[i] + boffs[blockIdx.x];
    if (i == n) rowptr[n] = ET;
}

__global__ void scatter_kernel(const int* __restrict__ ei, const int* __restrict__ rowptr,
                               int* __restrict__ cursor, int* __restrict__ srcs,
                               int E, int ET, const int* __restrict__ flags) {
    int e = blockIdx.x * 256 + threadIdx.x;
    if (e >= ET) return;
    int s_, d_;
    edge_sd(ei, e, E, flags[0], s_, d_);
    int pos = atomicAdd(&cursor[d_], 1);
    srcs[rowptr[d_] + pos] = s_;
}

// ========== graph boundaries via binary search (batch is sorted, no atomics) =
__global__ void goff_bs_kernel(const int* __restrict__ bt, int* __restrict__ goff,
                               int* __restrict__ gcnt, const int* __restrict__ flags) {
    int is64 = flags[0];
    int t = threadIdx.x;  // 0..127
    if (t <= NG) {
        int lo = 0, hi = NNODES;
        while (lo < hi) {  // first n with batch[n] >= t
            int mid = (lo + hi) >> 1;
            int b = clampG(is64 ? bt[2 * mid] : bt[mid]);
            if (b < t) lo = mid + 1; else hi = mid;
        }
        goff[t] = lo;
    }
    __syncthreads();
    if (t < NG) gcnt[t] = goff[t + 1] - goff[t];
}

// ======================= dtype-normalizing prep kernels ======================
__global__ void cast_kernel(const void* __restrict__ x, short* __restrict__ xb,
                            const int* __restrict__ flags, int total) {
    int i = blockIdx.x * 256 + threadIdx.x;
    if (i >= total) return;
    xb[i] = f2bfbits(ldf(x, i, flags[1]));
}

// W [256x256] row-major -> fragment-linear B for mfma_f32_16x16x32_bf16:
// Bf[((kt*16 + ctile)*64 + lane)*8 + j] = W[kt*32 + (lane>>4)*8 + j][ctile*16 + (lane&15)]
__global__ void repack_kernel(const void* __restrict__ W, short* __restrict__ Bf,
                              const int* __restrict__ flags) {
    int i = blockIdx.x * 256 + threadIdx.x;  // 65536
    int j = i & 7, lane = (i >> 3) & 63, tile = i >> 9;
    int kt = tile >> 4, ctg = tile & 15;
    int k = kt * 32 + (lane >> 4) * 8 + j;
    int n = ctg * 16 + (lane & 15);
    Bf[i] = f2bfbits(ldf(W, k * NF + n, flags[1]));
}

// ======================= MFMA GEMM: C[M,256] = A[M,256] @ B[256,256] =========
__global__ __launch_bounds__(256) void gemm_mfma(const short* __restrict__ A,
                                                 const short* __restrict__ Bf,
                                                 bf16* __restrict__ C, int M) {
    int wave = threadIdx.x >> 6;
    int lane = threadIdx.x & 63;
    int am = lane & 15, aq = lane >> 4;
    int row0 = blockIdx.x * 64;
    floatx4 acc[4][4];
    #pragma unroll
    for (int i = 0; i < 4; i++)
        #pragma unroll
        for (int j = 0; j < 4; j++) acc[i][j] = (floatx4){0.f, 0.f, 0.f, 0.f};
    for (int kt = 0; kt < 8; kt++) {
        short8 a[4], b[4];
        #pragma unroll
        for (int rt = 0; rt < 4; rt++)
            a[rt] = *(const short8*)&A[(row0 + rt * 16 + am) * NF + kt * 32 + aq * 8];
        #pragma unroll
        for (int ct = 0; ct < 4; ct++)
            b[ct] = *(const short8*)&Bf[((kt * 16 + wave * 4 + ct) * 64 + lane) * 8];
        #pragma unroll
        for (int rt = 0; rt < 4; rt++)
            #pragma unroll
            for (int ct = 0; ct < 4; ct++)
                acc[rt][ct] = __builtin_amdgcn_mfma_f32_16x16x32_bf16(a[rt], b[ct], acc[rt][ct], 0, 0, 0);
    }
    int rbase = (lane >> 4) * 4;
    int cbase = wave * 64 + (lane & 15);
    #pragma unroll
    for (int rt = 0; rt < 4; rt++) {
        #pragma unroll
        for (int r = 0; r < 4; r++) {
            int row = row0 + rt * 16 + rbase + r;
            if (row < M) {
                #pragma unroll
                for (int ct = 0; ct < 4; ct++)
                    C[row * NF + cbase + ct * 16] = __float2bfloat16(acc[rt][ct][r]);
            }
        }
    }
}

// ---- per-node attention logits ---------------------------------------------
__global__ void att_kernel(const bf16* __restrict__ h, const void* __restrict__ att_s,
                           const void* __restrict__ att_d,
                           float* __restrict__ a_src, float* __restrict__ a_dst,
                           const int* __restrict__ flags) {
    int isbf = flags[1];
    int n = blockIdx.x;
    int t = threadIdx.x;
    float hv = __bfloat162float(h[n * NF + t]);
    float vs = hv * ldf(att_s, t, isbf);
    float vd = hv * ldf(att_d, t, isbf);
    #pragma unroll
    for (int off = 32; off > 0; off >>= 1) {
        vs += __shfl_down(vs, off, 64);
        vd += __shfl_down(vd, off, 64);
    }
    if ((t & 63) == 0) {
        a_src[n * NH + (t >> 6)] = vs;
        a_dst[n * NH + (t >> 6)] = vd;
    }
}

__device__ inline float leaky_clamp(float v) {
    v = v > 0.f ? v : 0.2f * v;
    return fminf(fmaxf(v, -30.f), 30.f);
}

// ---- fused per-dst softmax + aggregate + bias + ELU + residual -------------
// 128 threads: thread t owns features {2t, 2t+1}; head = t>>5.
// Inner loop: one 4B load (2 bf16) + 2 FMAs per edge per thread.
__global__ __launch_bounds__(128) void agg_csr_kernel(
        const int* __restrict__ rowptr, const int* __restrict__ srcs,
        const float* __restrict__ asrc, const float* __restrict__ adst,
        const bf16* __restrict__ h, const void* __restrict__ bias,
        const void* __restrict__ resid, float* __restrict__ agg,
        const int* __restrict__ flags, int residFollows) {
    int d = blockIdx.x;
    int t = threadIdx.x;        // 0..127
    int hh = t >> 5;            // head for my feature pair
    int l32 = t & 31;
    int isbf = flags[1];
    int rIsBf = residFollows ? isbf : 1;
    int beg = rowptr[d], end = rowptr[d + 1];
    __shared__ float sden[NH];
    __shared__ float sinv[NH];
    __shared__ float sad[NH];
    if (t < NH) sad[t] = adst[d * NH + t];
    __syncthreads();
    // phase 1: per-head softmax denominator (32 lanes per head)
    float ad = sad[hh];
    float part = 0.f;
    for (int k = beg + l32; k < end; k += 32)
        part += __expf(leaky_clamp(asrc[srcs[k] * NH + hh] + ad));
    #pragma unroll
    for (int off = 16; off > 0; off >>= 1) part += __shfl_down(part, off, 32);
    if (l32 == 0) sden[hh] = part;
    __syncthreads();
    if (t < NH) sinv[t] = 1.f / fmaxf(sden[t], 1e-30f);
    __syncthreads();
    // phase 2: chunks of 64 edges; lane-parallel alphas, broadcast gather
    __shared__ int sSrc[64];
    __shared__ float sAl[NH][64];
    float acc0 = 0.f, acc1 = 0.f;
    int e = t & 63, wv = t >> 6;
    for (int cb = beg; cb < end; cb += 64) {
        int nk = min(64, end - cb);
        if (t < 64 && e < nk) sSrc[e] = srcs[cb + e];
        #pragma unroll
        for (int sub = 0; sub < 2; sub++) {
            int head = wv * 2 + sub;
            if (e < nk) {
                int s = srcs[cb + e];
                sAl[head][e] = __expf(leaky_clamp(asrc[s * NH + head] + sad[head])) * sinv[head];
            }
        }
        __syncthreads();
        for (int k = 0; k < nk; k++) {
            float al = sAl[hh][k];
            unsigned hv = *(const unsigned*)&h[sSrc[k] * NF + 2 * t];
            acc0 += al * __uint_as_float(hv << 16);
            acc1 += al * __uint_as_float(hv & 0xFFFF0000u);
        }
        __syncthreads();
    }
    // epilogue: + bias, ELU, + residual (2 features per thread)
    float b0 = ldf(bias, 2 * t, isbf), b1 = ldf(bias, 2 * t + 1, isbf);
    float2 r = ld2f(resid, d * NF + 2 * t, rIsBf);
    float v0 = acc0 + b0, v1 = acc1 + b1;
    v0 = v0 > 0.f ? v0 : (__expf(v0) - 1.0f);
    v1 = v1 > 0.f ? v1 : (__expf(v1) - 1.0f);
    *(float2*)&agg[d * NF + 2 * t] = make_float2(v0 + r.x, v1 + r.y);
}

__global__ void bn_stats_kernel(const float* __restrict__ x, float* __restrict__ bsum,
                                float* __restrict__ bsumsq) {
    int f = threadIdx.x;
    float s = 0.f, sq = 0.f;
    for (int r = blockIdx.x; r < NNODES; r += gridDim.x) {
        float v = x[r * NF + f];
        s += v;
        sq += v * v;
    }
    atomicAdd(&bsum[f], s);
    atomicAdd(&bsumsq[f], sq);
}

template <typename OT>
__global__ void bn_norm_kernel(const float* __restrict__ x, const float* __restrict__ bsum,
                               const float* __restrict__ bsumsq,
                               const void* __restrict__ gamma, const void* __restrict__ beta,
                               OT* __restrict__ out, int total, const int* __restrict__ flags) {
    int i = blockIdx.x * blockDim.x + threadIdx.x;
    if (i >= total) return;
    int isbf = flags[1];
    const float invN = 1.0f / (float)NNODES;
    int f = i & (NF - 1);
    float mu = bsum[f] * invN;
    float var = fmaxf(bsumsq[f] * invN - mu * mu, 0.f);
    float v = (x[i] - mu) * rsqrtf(var + 1e-5f);
    stOut(out[i], ldf(gamma, f, isbf) * v + ldf(beta, f, isbf));
}

// ---- pooling: contiguous node slices per graph (batch is sorted) -----------
__global__ void pool2_kernel(const float* __restrict__ x, const int* __restrict__ goff,
                             float* __restrict__ pooled) {
    int g = blockIdx.x >> 3, c = blockIdx.x & 7, t = threadIdx.x;
    int beg = goff[g], end = goff[g + 1];
    int len = end - beg;
    if (len <= 0) return;
    int chunk = (len + 7) >> 3;
    int s0 = beg + c * chunk;
    int s1 = min(s0 + chunk, end);
    if (s0 >= s1) return;
    float acc = 0.f;
    for (int n = s0; n < s1; n++) acc += x[n * NF + t];
    atomicAdd(&pooled[g * NF + t], acc);
}

__global__ void head_kernel(const float* __restrict__ pooled, const int* __restrict__ gcnt,
                            const void* __restrict__ fc1w, const void* __restrict__ fc1b,
                            const void* __restrict__ fc2w, const void* __restrict__ fc2b,
                            void* __restrict__ out, const int* __restrict__ flags) {
    int g = blockIdx.x;
    int t = threadIdx.x;  // 64
    int isbf = flags[1];
    __shared__ float p[NF];
    __shared__ float z[64];
    __shared__ float logits[NCLS];
    __shared__ float lse;
    float c = fmaxf((float)gcnt[g], 1.f);
    float invc = 1.f / c;
    for (int i = t; i < NF; i += 64) p[i] = pooled[g * NF + i] * invc;
    __syncthreads();
    float acc = ldf(fc1b, t, isbf);
    for (int k = 0; k < NF; k++) acc += p[k] * ldf(fc1w, k * 64 + t, isbf);
    z[t] = acc > 0.f ? acc : 0.f;
    __syncthreads();
    if (t < NCLS) {
        float a2 = ldf(fc2b, t, isbf);
        for (int k = 0; k < 64; k++) a2 += z[k] * ldf(fc2w, k * NCLS + t, isbf);
        logits[t] = a2;
    }
    __syncthreads();
    if (t == 0) {
        float mx = logits[0];
        for (int j = 1; j < NCLS; j++) mx = fmaxf(mx, logits[j]);
        float se = 0.f;
        for (int j = 0; j < NCLS; j++) se += expf(logits[j] - mx);
        lse = mx + logf(se);
    }
    __syncthreads();
    if (t < NCLS) stf(out, g * NCLS + t, logits[t] - lse, isbf);
}

extern "C" void kernel_launch(void* const* d_in, const int* in_sizes, int n_in,
                              void* d_out, int out_size, void* d_ws, size_t ws_size,
                              hipStream_t stream) {
    const void* x = d_in[0];
    const int* edge_index = (const int*)d_in[1];
    const int* batch = (const int*)d_in[2];
    const void* W1 = d_in[3];
    const void* att_src1 = d_in[4];
    const void* att_dst1 = d_in[5];
    const void* b1 = d_in[6];
    const void* gamma1 = d_in[7];
    const void* beta1 = d_in[8];
    const void* W2 = d_in[9];
    const void* att_src2 = d_in[10];
    const void* att_dst2 = d_in[11];
    const void* b2 = d_in[12];
    const void* gamma2 = d_in[13];
    const void* beta2 = d_in[14];
    const void* fc1w = d_in[15];
    const void* fc1b = d_in[16];
    const void* fc2w = d_in[17];
    const void* fc2b = d_in[18];

    const int E = in_sizes[1] / 2;     // 400000
    const int ET = E + NNODES;         // + self-loops
    const int NE = NNODES * NF;
    const int NNH = NNODES * NH;
    const int NB = (NNODES + 255) / 256;
    const int NB1 = (NNODES + 1 + 255) / 256;

    // ---- workspace layout ----
    float* ws = (float*)d_ws;
    float* agg = ws;                       // N*256 fp32 (also aliases xb during GEMM1)
    float* asrc = agg + NE;                // N*4 (also aliases scan scratch)
    float* adst = asrc + NNH;              // N*4
    int* flags = (int*)(adst + NNH);       // 16
    bf16* hb = (bf16*)(flags + 16);        // N*256 bf16
    bf16* l1ob = hb + NE;                  // MPAD*256 bf16 (padded for gemm A reads)
    int* rowptr = (int*)(l1ob + (size_t)MPAD * NF);  // N+1 (+pad)
    int* srcs = rowptr + NNODES + 16;      // ET
    int* goff = srcs + ET + 16;            // NG+1
    // zero region (single memset): deg, cursor, gcnt, pooled, bnstat
    int* deg = goff + NG + 1 + 14;
    int* cursor = deg + NNODES;
    int* gcnt = cursor + NNODES;
    float* pooled = (float*)(gcnt + NG);   // 64*256
    float* bnstat = pooled + NG * NF;      // 4*256
    size_t zero_bytes = (size_t)(2 * NNODES + NG) * 4 + (size_t)(NG * NF + 4 * NF) * 4;
    short* Bf1 = (short*)(bnstat + 4 * NF);  // 65536 (outside zero region)
    short* Bf2 = Bf1 + NF * NF;              // 65536
    // scan scratch aliased onto asrc/adst (overwritten later by att_kernel)
    int* eprefix = (int*)asrc;
    int* bsums = eprefix + NNODES + 16;
    int* boffs = bsums + 256;
    // xb aliased onto agg (agg first written by agg_csr, after GEMM1 consumed xb)
    short* xb = (short*)agg;               // MPAD*256 bf16 bits

    float* bnsum1 = bnstat;
    float* bnsq1 = bnstat + NF;
    float* bnsum2 = bnstat + 2 * NF;
    float* bnsq2 = bnstat + 3 * NF;

    detect_kernel<<<1, 256, 0, stream>>>(edge_index, (const unsigned*)W1, flags);
    hipMemsetAsync(deg, 0, zero_bytes, stream);

    // ---- dtype-normalize inputs for MFMA ----
    cast_kernel<<<(NE + 255) / 256, 256, 0, stream>>>(x, xb, flags, NE);
    repack_kernel<<<NF * NF / 256, 256, 0, stream>>>(W1, Bf1, flags);
    repack_kernel<<<NF * NF / 256, 256, 0, stream>>>(W2, Bf2, flags);

    // ---- CSR build + graph boundaries (reused by both layers) ----
    deg_kernel<<<(ET + 255) / 256, 256, 0, stream>>>(edge_index, deg, E, ET, flags);
    scan1_kernel<<<NB, 256, 0, stream>>>(deg, eprefix, bsums, NNODES);
    scan2_kernel<<<1, 256, 0, stream>>>(bsums, boffs, NB);
    scan3_kernel<<<NB1, 256, 0, stream>>>(eprefix, boffs, rowptr, NNODES, ET);
    scatter_kernel<<<(ET + 255) / 256, 256, 0, stream>>>(edge_index, rowptr, cursor, srcs, E, ET, flags);
    goff_bs_kernel<<<1, 128, 0, stream>>>(batch, goff, gcnt, flags);

    // ================= layer 1 =================
    gemm_mfma<<<MPAD / 64, 256, 0, stream>>>(xb, Bf1, hb, NNODES);
    att_kernel<<<NNODES, 256, 0, stream>>>(hb, att_src1, att_dst1, asrc, adst, flags);
    agg_csr_kernel<<<NNODES, 128, 0, stream>>>(rowptr, srcs, asrc, adst, hb, b1, x, agg, flags, 1);
    bn_stats_kernel<<<512, 256, 0, stream>>>(agg, bnsum1, bnsq1);
    bn_norm_kernel<bf16><<<(NE + 255) / 256, 256, 0, stream>>>(agg, bnsum1, bnsq1, gamma1, beta1, l1ob, NE, flags);

    // ================= layer 2 =================
    gemm_mfma<<<MPAD / 64, 256, 0, stream>>>((const short*)l1ob, Bf2, hb, NNODES);
    att_kernel<<<NNODES, 256, 0, stream>>>(hb, att_src2, att_dst2, asrc, adst, flags);
    agg_csr_kernel<<<NNODES, 128, 0, stream>>>(rowptr, srcs, asrc, adst, hb, b2, l1ob, agg, flags, 0);
    bn_stats_kernel<<<512, 256, 0, stream>>>(agg, bnsum2, bnsq2);
    bn_norm_kernel<float><<<(NE + 255) / 256, 256, 0, stream>>>(agg, bnsum2, bnsq2, gamma2, beta2, agg, NE, flags);

    // ================= pool + head =================
    pool2_kernel<<<NG * 8, 256, 0, stream>>>(agg, goff, pooled);
    head_kernel<<<NG, 64, 0, stream>>>(pooled, gcnt, fc1w, fc1b, fc2w, fc2b, d_out, flags);
}

// Round 8
// 568.639 us; speedup vs baseline: 3.8804x; 1.1295x over previous
//
#include <hip/hip_runtime.h>
#include <hip/hip_bf16.h>

#define NNODES 50000
#define NF 256
#define NH 4
#define NG 64
#define NCLS 10
#define MPAD 50048  // NNODES rounded up to multiple of 64 (gemm row padding)

typedef __hip_bfloat16 bf16;
typedef __attribute__((ext_vector_type(8))) short short8;   // 8 bf16 = 4 VGPRs
typedef __attribute__((ext_vector_type(4))) float floatx4;  // MFMA accumulator

// flags[0] = indices are int64 ; flags[1] = floats are bf16
__device__ inline float ldf(const void* p, int i, int isbf) {
    return isbf ? __bfloat162float(((const bf16*)p)[i]) : ((const float*)p)[i];
}
__device__ inline float2 ld2f(const void* p, int i, int isbf) {
    if (isbf) {
        unsigned u = *(const unsigned*)((const short*)p + i);
        return make_float2(__uint_as_float(u << 16), __uint_as_float(u & 0xFFFF0000u));
    }
    return *(const float2*)((const float*)p + i);
}
__device__ inline void stf(void* p, int i, float v, int isbf) {
    if (isbf) ((bf16*)p)[i] = __float2bfloat16(v);
    else ((float*)p)[i] = v;
}
__device__ inline short f2bfbits(float v) {
    bf16 b = __float2bfloat16(v);
    return *reinterpret_cast<short*>(&b);
}
__device__ inline void stOut(float& d, float v) { d = v; }
__device__ inline void stOut(bf16& d, float v) { d = __float2bfloat16(v); }
__device__ inline int clampN(int v) { return ((unsigned)v < (unsigned)NNODES) ? v : 0; }
__device__ inline int clampG(int v) { return ((unsigned)v < (unsigned)NG) ? v : 0; }

__global__ void detect_kernel(const int* __restrict__ ei, const unsigned* __restrict__ w1,
                              int* __restrict__ flags) {
    __shared__ int nzOdd, insane;
    if (threadIdx.x == 0) { nzOdd = 0; insane = 0; }
    __syncthreads();
    if (ei[2 * threadIdx.x + 1] != 0) atomicAdd(&nzOdd, 1);
    unsigned lo = w1[threadIdx.x] & 0xFFFFu;
    unsigned ex = (lo >> 7) & 0xFFu;
    bool sane = ((lo & 0x7FFFu) == 0u) || (ex >= 90u && ex <= 133u);
    if (!sane) atomicAdd(&insane, 1);
    __syncthreads();
    if (threadIdx.x == 0) {
        flags[0] = (nzOdd == 0) ? 1 : 0;
        flags[1] = (insane == 0) ? 1 : 0;
    }
}

__device__ inline void edge_sd(const int* __restrict__ ei, int e, int E, int is64,
                               int& s_, int& d_) {
    if (e < E) {
        if (is64) { s_ = ei[2 * e]; d_ = ei[2 * E + 2 * e]; }
        else      { s_ = ei[e];     d_ = ei[E + e]; }
    } else {
        s_ = d_ = e - E;  // self-loop
    }
    s_ = clampN(s_);
    d_ = clampN(d_);
}

// ======================= CSR build (once, reused both layers) ================
__global__ void deg_kernel(const int* __restrict__ ei, int* __restrict__ deg,
                           int E, int ET, const int* __restrict__ flags) {
    int e = blockIdx.x * 256 + threadIdx.x;
    if (e >= ET) return;
    int s_, d_;
    edge_sd(ei, e, E, flags[0], s_, d_);
    atomicAdd(&deg[d_], 1);
}

__global__ void scan1_kernel(const int* __restrict__ deg, int* __restrict__ eprefix,
                             int* __restrict__ bsums, int n) {
    __shared__ int sc[256];
    int t = threadIdx.x, i = blockIdx.x * 256 + t;
    int val = (i < n) ? deg[i] : 0;
    sc[t] = val;
    __syncthreads();
    for (int off = 1; off < 256; off <<= 1) {
        int tmp = (t >= off) ? sc[t - off] : 0;
        __syncthreads();
        sc[t] += tmp;
        __syncthreads();
    }
    if (i < n) eprefix[i] = sc[t] - val;
    if (t == 255) bsums[blockIdx.x] = sc[255];
}

__global__ void scan2_kernel(const int* __restrict__ bsums, int* __restrict__ boffs, int nb) {
    __shared__ int sc[256];
    int t = threadIdx.x;
    int val = (t < nb) ? bsums[t] : 0;
    sc[t] = val;
    __syncthreads();
    for (int off = 1; off < 256; off <<= 1) {
        int tmp = (t >= off) ? sc[t - off] : 0;
        __syncthreads();
        sc[t] += tmp;
        __syncthreads();
    }
    if (t < nb) boffs[t] = sc[t] - val;
}

__global__ void scan3_kernel(const int* __restrict__ eprefix, const int* __restrict__ boffs,
                             int* __restrict__ rowptr, int n, int ET) {
    int i = blockIdx.x * 256 + threadIdx.x;
    if (i < n) rowptr[i] = eprefix[i] + boffs[blockIdx.x];
    if (i == n) rowptr[n] = ET;
}

__global__ void scatter_kernel(const int* __restrict__ ei, const int* __restrict__ rowptr,
                               int* __restrict__ cursor, int* __restrict__ srcs,
                               int E, int ET, const int* __restrict__ flags) {
    int e = blockIdx.x * 256 + threadIdx.x;
    if (e >= ET) return;
    int s_, d_;
    edge_sd(ei, e, E, flags[0], s_, d_);
    int pos = atomicAdd(&cursor[d_], 1);
    srcs[rowptr[d_] + pos] = s_;
}

// ========== graph boundaries via binary search (batch is sorted, no atomics) =
__global__ void goff_bs_kernel(const int* __restrict__ bt, int* __restrict__ goff,
                               int* __restrict__ gcnt, const int* __restrict__ flags) {
    int is64 = flags[0];
    int t = threadIdx.x;  // 0..127
    if (t <= NG) {
        int lo = 0, hi = NNODES;
        while (lo < hi) {
            int mid = (lo + hi) >> 1;
            int b = clampG(is64 ? bt[2 * mid] : bt[mid]);
            if (b < t) lo = mid + 1; else hi = mid;
        }
        goff[t] = lo;
    }
    __syncthreads();
    if (t < NG) gcnt[t] = goff[t + 1] - goff[t];
}

// W [256x256] row-major -> fragment-linear B for mfma_f32_16x16x32_bf16:
__global__ void repack_kernel(const void* __restrict__ W, short* __restrict__ Bf,
                              const int* __restrict__ flags) {
    int i = blockIdx.x * 256 + threadIdx.x;  // 65536
    int j = i & 7, lane = (i >> 3) & 63, tile = i >> 9;
    int kt = tile >> 4, ctg = tile & 15;
    int k = kt * 32 + (lane >> 4) * 8 + j;
    int n = ctg * 16 + (lane & 15);
    Bf[i] = f2bfbits(ldf(W, k * NF + n, flags[1]));
}

// ====== MFMA GEMM + fused attention-logit epilogue ===========================
// C[M,256] = A[M,256] @ B[256,256]; also a_src[n][h] = C[n]·att_s[h], likewise a_dst.
// head h == wave w (wave covers cols w*64..w*64+63). A dtype runtime-switched.
__global__ __launch_bounds__(256) void gemm_mfma(
        const void* __restrict__ A, const short* __restrict__ Bf, bf16* __restrict__ C,
        int M, const int* __restrict__ flags, int aFollows,
        const void* __restrict__ att_s, const void* __restrict__ att_d,
        float* __restrict__ a_src, float* __restrict__ a_dst) {
    int isbf = flags[1];
    int aIsBf = aFollows ? isbf : 1;
    int wave = threadIdx.x >> 6;
    int lane = threadIdx.x & 63;
    int am = lane & 15, aq = lane >> 4;
    int row0 = blockIdx.x * 64;
    // att fragment registers: my wave's 64-col slice
    float attS[4], attD[4];
    #pragma unroll
    for (int ct = 0; ct < 4; ct++) {
        int col = wave * 64 + ct * 16 + am;
        attS[ct] = ldf(att_s, col, isbf);
        attD[ct] = ldf(att_d, col, isbf);
    }
    int rowA[4];
    #pragma unroll
    for (int rt = 0; rt < 4; rt++) rowA[rt] = min(row0 + rt * 16 + am, M - 1);
    floatx4 acc[4][4];
    #pragma unroll
    for (int i = 0; i < 4; i++)
        #pragma unroll
        for (int j = 0; j < 4; j++) acc[i][j] = (floatx4){0.f, 0.f, 0.f, 0.f};
    for (int kt = 0; kt < 8; kt++) {
        short8 a[4], b[4];
        if (aIsBf) {
            #pragma unroll
            for (int rt = 0; rt < 4; rt++)
                a[rt] = *(const short8*)((const short*)A + rowA[rt] * NF + kt * 32 + aq * 8);
        } else {
            #pragma unroll
            for (int rt = 0; rt < 4; rt++) {
                const float* fp = (const float*)A + rowA[rt] * NF + kt * 32 + aq * 8;
                float4 f0 = *(const float4*)fp;
                float4 f1 = *(const float4*)(fp + 4);
                short8 v;
                v[0] = f2bfbits(f0.x); v[1] = f2bfbits(f0.y);
                v[2] = f2bfbits(f0.z); v[3] = f2bfbits(f0.w);
                v[4] = f2bfbits(f1.x); v[5] = f2bfbits(f1.y);
                v[6] = f2bfbits(f1.z); v[7] = f2bfbits(f1.w);
                a[rt] = v;
            }
        }
        #pragma unroll
        for (int ct = 0; ct < 4; ct++)
            b[ct] = *(const short8*)&Bf[((kt * 16 + wave * 4 + ct) * 64 + lane) * 8];
        #pragma unroll
        for (int rt = 0; rt < 4; rt++)
            #pragma unroll
            for (int ct = 0; ct < 4; ct++)
                acc[rt][ct] = __builtin_amdgcn_mfma_f32_16x16x32_bf16(a[rt], b[ct], acc[rt][ct], 0, 0, 0);
    }
    // C store (col = lane&15, row = (lane>>4)*4 + reg)
    int rbase = (lane >> 4) * 4;
    int cbase = wave * 64 + am;
    #pragma unroll
    for (int rt = 0; rt < 4; rt++) {
        #pragma unroll
        for (int r = 0; r < 4; r++) {
            int row = row0 + rt * 16 + rbase + r;
            if (row < M) {
                #pragma unroll
                for (int ct = 0; ct < 4; ct++)
                    C[row * NF + cbase + ct * 16] = __float2bfloat16(acc[rt][ct][r]);
            }
        }
    }
    // attention-logit epilogue: per (rt,r) reduce 16 col-lanes
    #pragma unroll
    for (int rt = 0; rt < 4; rt++) {
        #pragma unroll
        for (int r = 0; r < 4; r++) {
            float ps = 0.f, pd = 0.f;
            #pragma unroll
            for (int ct = 0; ct < 4; ct++) {
                float v = acc[rt][ct][r];
                ps += v * attS[ct];
                pd += v * attD[ct];
            }
            #pragma unroll
            for (int m = 1; m <= 8; m <<= 1) {
                ps += __shfl_xor(ps, m, 64);
                pd += __shfl_xor(pd, m, 64);
            }
            int row = row0 + rt * 16 + rbase + r;
            if (am == 0 && row < M) {
                a_src[row * NH + wave] = ps;
                a_dst[row * NH + wave] = pd;
            }
        }
    }
}

__device__ inline float leaky_clamp(float v) {
    v = v > 0.f ? v : 0.2f * v;
    return fminf(fmaxf(v, -30.f), 30.f);
}

// ---- fused per-dst softmax + aggregate + bias + ELU + residual -------------
// 128 threads: thread t owns features {2t, 2t+1}; head = t>>5.
__global__ __launch_bounds__(128) void agg_csr_kernel(
        const int* __restrict__ rowptr, const int* __restrict__ srcs,
        const float* __restrict__ asrc, const float* __restrict__ adst,
        const bf16* __restrict__ h, const void* __restrict__ bias,
        const void* __restrict__ resid, float* __restrict__ agg,
        const int* __restrict__ flags, int residFollows) {
    int d = blockIdx.x;
    int t = threadIdx.x;        // 0..127
    int hh = t >> 5;
    int l32 = t & 31;
    int isbf = flags[1];
    int rIsBf = residFollows ? isbf : 1;
    int beg = rowptr[d], end = rowptr[d + 1];
    __shared__ float sden[NH];
    __shared__ float sinv[NH];
    __shared__ float sad[NH];
    if (t < NH) sad[t] = adst[d * NH + t];
    __syncthreads();
    float ad = sad[hh];
    float part = 0.f;
    for (int k = beg + l32; k < end; k += 32)
        part += __expf(leaky_clamp(asrc[srcs[k] * NH + hh] + ad));
    #pragma unroll
    for (int off = 16; off > 0; off >>= 1) part += __shfl_down(part, off, 32);
    if (l32 == 0) sden[hh] = part;
    __syncthreads();
    if (t < NH) sinv[t] = 1.f / fmaxf(sden[t], 1e-30f);
    __syncthreads();
    __shared__ int sSrc[64];
    __shared__ float sAl[NH][64];
    float acc0 = 0.f, acc1 = 0.f;
    int e = t & 63, wv = t >> 6;
    for (int cb = beg; cb < end; cb += 64) {
        int nk = min(64, end - cb);
        if (t < 64 && e < nk) sSrc[e] = srcs[cb + e];
        #pragma unroll
        for (int sub = 0; sub < 2; sub++) {
            int head = wv * 2 + sub;
            if (e < nk) {
                int s = srcs[cb + e];
                sAl[head][e] = __expf(leaky_clamp(asrc[s * NH + head] + sad[head])) * sinv[head];
            }
        }
        __syncthreads();
        int k = 0;
        for (; k + 4 <= nk; k += 4) {
            unsigned u0 = *(const unsigned*)&h[sSrc[k] * NF + 2 * t];
            unsigned u1 = *(const unsigned*)&h[sSrc[k + 1] * NF + 2 * t];
            unsigned u2 = *(const unsigned*)&h[sSrc[k + 2] * NF + 2 * t];
            unsigned u3 = *(const unsigned*)&h[sSrc[k + 3] * NF + 2 * t];
            float a0 = sAl[hh][k], a1 = sAl[hh][k + 1], a2 = sAl[hh][k + 2], a3 = sAl[hh][k + 3];
            acc0 += a0 * __uint_as_float(u0 << 16);
            acc1 += a0 * __uint_as_float(u0 & 0xFFFF0000u);
            acc0 += a1 * __uint_as_float(u1 << 16);
            acc1 += a1 * __uint_as_float(u1 & 0xFFFF0000u);
            acc0 += a2 * __uint_as_float(u2 << 16);
            acc1 += a2 * __uint_as_float(u2 & 0xFFFF0000u);
            acc0 += a3 * __uint_as_float(u3 << 16);
            acc1 += a3 * __uint_as_float(u3 & 0xFFFF0000u);
        }
        for (; k < nk; k++) {
            float al = sAl[hh][k];
            unsigned hv = *(const unsigned*)&h[sSrc[k] * NF + 2 * t];
            acc0 += al * __uint_as_float(hv << 16);
            acc1 += al * __uint_as_float(hv & 0xFFFF0000u);
        }
        __syncthreads();
    }
    float b0 = ldf(bias, 2 * t, isbf), b1 = ldf(bias, 2 * t + 1, isbf);
    float2 r = ld2f(resid, d * NF + 2 * t, rIsBf);
    float v0 = acc0 + b0, v1 = acc1 + b1;
    v0 = v0 > 0.f ? v0 : (__expf(v0) - 1.0f);
    v1 = v1 > 0.f ? v1 : (__expf(v1) - 1.0f);
    *(float2*)&agg[d * NF + 2 * t] = make_float2(v0 + r.x, v1 + r.y);
}

__global__ void bn_stats_kernel(const float* __restrict__ x, float* __restrict__ bsum,
                                float* __restrict__ bsumsq) {
    int f = threadIdx.x;
    float s = 0.f, sq = 0.f;
    for (int r = blockIdx.x; r < NNODES; r += gridDim.x) {
        float v = x[r * NF + f];
        s += v;
        sq += v * v;
    }
    atomicAdd(&bsum[f], s);
    atomicAdd(&bsumsq[f], sq);
}

template <typename OT>
__global__ void bn_norm_kernel(const float* __restrict__ x, const float* __restrict__ bsum,
                               const float* __restrict__ bsumsq,
                               const void* __restrict__ gamma, const void* __restrict__ beta,
                               OT* __restrict__ out, int total, const int* __restrict__ flags) {
    int i = blockIdx.x * blockDim.x + threadIdx.x;
    if (i >= total) return;
    int isbf = flags[1];
    const float invN = 1.0f / (float)NNODES;
    int f = i & (NF - 1);
    float mu = bsum[f] * invN;
    float var = fmaxf(bsumsq[f] * invN - mu * mu, 0.f);
    float v = (x[i] - mu) * rsqrtf(var + 1e-5f);
    stOut(out[i], ldf(gamma, f, isbf) * v + ldf(beta, f, isbf));
}

// ---- pooling: contiguous node slices per graph (batch is sorted) -----------
__global__ void pool2_kernel(const float* __restrict__ x, const int* __restrict__ goff,
                             float* __restrict__ pooled) {
    int g = blockIdx.x >> 3, c = blockIdx.x & 7, t = threadIdx.x;
    int beg = goff[g], end = goff[g + 1];
    int len = end - beg;
    if (len <= 0) return;
    int chunk = (len + 7) >> 3;
    int s0 = beg + c * chunk;
    int s1 = min(s0 + chunk, end);
    if (s0 >= s1) return;
    float acc = 0.f;
    for (int n = s0; n < s1; n++) acc += x[n * NF + t];
    atomicAdd(&pooled[g * NF + t], acc);
}

// head: applies layer-2 BN affine to pooled means (BN commutes with mean-pool)
__global__ void head_kernel(const float* __restrict__ pooled, const int* __restrict__ gcnt,
                            const float* __restrict__ bnsum2, const float* __restrict__ bnsq2,
                            const void* __restrict__ gamma2, const void* __restrict__ beta2,
                            const void* __restrict__ fc1w, const void* __restrict__ fc1b,
                            const void* __restrict__ fc2w, const void* __restrict__ fc2b,
                            void* __restrict__ out, const int* __restrict__ flags) {
    int g = blockIdx.x;
    int t = threadIdx.x;  // 64
    int isbf = flags[1];
    __shared__ float p[NF];
    __shared__ float z[64];
    __shared__ float logits[NCLS];
    __shared__ float lse;
    float c = fmaxf((float)gcnt[g], 1.f);
    float invc = 1.f / c;
    const float invN = 1.0f / (float)NNODES;
    for (int i = t; i < NF; i += 64) {
        float mu = bnsum2[i] * invN;
        float var = fmaxf(bnsq2[i] * invN - mu * mu, 0.f);
        float pm = pooled[g * NF + i] * invc;
        p[i] = ldf(gamma2, i, isbf) * ((pm - mu) * rsqrtf(var + 1e-5f)) + ldf(beta2, i, isbf);
    }
    __syncthreads();
    float acc = ldf(fc1b, t, isbf);
    for (int k = 0; k < NF; k++) acc += p[k] * ldf(fc1w, k * 64 + t, isbf);
    z[t] = acc > 0.f ? acc : 0.f;
    __syncthreads();
    if (t < NCLS) {
        float a2 = ldf(fc2b, t, isbf);
        for (int k = 0; k < 64; k++) a2 += z[k] * ldf(fc2w, k * NCLS + t, isbf);
        logits[t] = a2;
    }
    __syncthreads();
    if (t == 0) {
        float mx = logits[0];
        for (int j = 1; j < NCLS; j++) mx = fmaxf(mx, logits[j]);
        float se = 0.f;
        for (int j = 0; j < NCLS; j++) se += expf(logits[j] - mx);
        lse = mx + logf(se);
    }
    __syncthreads();
    if (t < NCLS) stf(out, g * NCLS + t, logits[t] - lse, isbf);
}

extern "C" void kernel_launch(void* const* d_in, const int* in_sizes, int n_in,
                              void* d_out, int out_size, void* d_ws, size_t ws_size,
                              hipStream_t stream) {
    const void* x = d_in[0];
    const int* edge_index = (const int*)d_in[1];
    const int* batch = (const int*)d_in[2];
    const void* W1 = d_in[3];
    const void* att_src1 = d_in[4];
    const void* att_dst1 = d_in[5];
    const void* b1 = d_in[6];
    const void* gamma1 = d_in[7];
    const void* beta1 = d_in[8];
    const void* W2 = d_in[9];
    const void* att_src2 = d_in[10];
    const void* att_dst2 = d_in[11];
    const void* b2 = d_in[12];
    const void* gamma2 = d_in[13];
    const void* beta2 = d_in[14];
    const void* fc1w = d_in[15];
    const void* fc1b = d_in[16];
    const void* fc2w = d_in[17];
    const void* fc2b = d_in[18];

    const int E = in_sizes[1] / 2;     // 400000
    const int ET = E + NNODES;         // + self-loops
    const int NE = NNODES * NF;
    const int NNH = NNODES * NH;
    const int NB = (NNODES + 255) / 256;
    const int NB1 = (NNODES + 1 + 255) / 256;

    // ---- workspace layout ----
    float* ws = (float*)d_ws;
    float* agg = ws;                       // N*256 fp32
    float* asrc = agg + NE;                // N*4 (aliases scan scratch early)
    float* adst = asrc + NNH;              // N*4
    int* flags = (int*)(adst + NNH);       // 16
    bf16* hb = (bf16*)(flags + 16);        // N*256 bf16
    bf16* l1ob = hb + NE;                  // MPAD*256 bf16 (padded for gemm A reads)
    int* rowptr = (int*)(l1ob + (size_t)MPAD * NF);  // N+1 (+pad)
    int* srcs = rowptr + NNODES + 16;      // ET
    int* goff = srcs + ET + 16;            // NG+1
    // zero region (single memset): deg, cursor, gcnt, pooled, bnstat
    int* deg = goff + NG + 1 + 14;
    int* cursor = deg + NNODES;
    int* gcnt = cursor + NNODES;
    float* pooled = (float*)(gcnt + NG);   // 64*256
    float* bnstat = pooled + NG * NF;      // 4*256
    size_t zero_bytes = (size_t)(2 * NNODES + NG) * 4 + (size_t)(NG * NF + 4 * NF) * 4;
    short* Bf1 = (short*)(bnstat + 4 * NF);  // 65536 (outside zero region)
    short* Bf2 = Bf1 + NF * NF;              // 65536
    // scan scratch aliased onto asrc/adst (overwritten later by gemm epilogue)
    int* eprefix = (int*)asrc;
    int* bsums = eprefix + NNODES + 16;
    int* boffs = bsums + 256;

    float* bnsum1 = bnstat;
    float* bnsq1 = bnstat + NF;
    float* bnsum2 = bnstat + 2 * NF;
    float* bnsq2 = bnstat + 3 * NF;

    detect_kernel<<<1, 256, 0, stream>>>(edge_index, (const unsigned*)W1, flags);
    hipMemsetAsync(deg, 0, zero_bytes, stream);

    repack_kernel<<<NF * NF / 256, 256, 0, stream>>>(W1, Bf1, flags);
    repack_kernel<<<NF * NF / 256, 256, 0, stream>>>(W2, Bf2, flags);

    // ---- CSR build + graph boundaries (reused by both layers) ----
    deg_kernel<<<(ET + 255) / 256, 256, 0, stream>>>(edge_index, deg, E, ET, flags);
    scan1_kernel<<<NB, 256, 0, stream>>>(deg, eprefix, bsums, NNODES);
    scan2_kernel<<<1, 256, 0, stream>>>(bsums, boffs, NB);
    scan3_kernel<<<NB1, 256, 0, stream>>>(eprefix, boffs, rowptr, NNODES, ET);
    scatter_kernel<<<(ET + 255) / 256, 256, 0, stream>>>(edge_index, rowptr, cursor, srcs, E, ET, flags);
    goff_bs_kernel<<<1, 128, 0, stream>>>(batch, goff, gcnt, flags);

    // ================= layer 1 =================
    gemm_mfma<<<MPAD / 64, 256, 0, stream>>>(x, Bf1, hb, NNODES, flags, 1,
                                             att_src1, att_dst1, asrc, adst);
    agg_csr_kernel<<<NNODES, 128, 0, stream>>>(rowptr, srcs, asrc, adst, hb, b1, x, agg, flags, 1);
    bn_stats_kernel<<<512, 256, 0, stream>>>(agg, bnsum1, bnsq1);
    bn_norm_kernel<bf16><<<(NE + 255) / 256, 256, 0, stream>>>(agg, bnsum1, bnsq1, gamma1, beta1, l1ob, NE, flags);

    // ================= layer 2 =================
    gemm_mfma<<<MPAD / 64, 256, 0, stream>>>(l1ob, Bf2, hb, NNODES, flags, 0,
                                             att_src2, att_dst2, asrc, adst);
    agg_csr_kernel<<<NNODES, 128, 0, stream>>>(rowptr, srcs, asrc, adst, hb, b2, l1ob, agg, flags, 0);
    bn_stats_kernel<<<512, 256, 0, stream>>>(agg, bnsum2, bnsq2);
    // no bn_norm for layer 2: BN affine applied to pooled means in head

    // ================= pool + head =================
    pool2_kernel<<<NG * 8, 256, 0, stream>>>(agg, goff, pooled);
    head_kernel<<<NG, 64, 0, stream>>>(pooled, gcnt, bnsum2, bnsq2, gamma2, beta2,
                                       fc1w, fc1b, fc2w, fc2b, d_out, flags);
}

// Round 10
// 494.380 us; speedup vs baseline: 4.4633x; 1.1502x over previous
//
#include <hip/hip_runtime.h>
#include <hip/hip_bf16.h>

#define NNODES 50000
#define NF 256
#define NH 4
#define NG 64
#define NCLS 10
#define MPAD 50048  // NNODES rounded up to multiple of 64 (gemm row padding)

typedef __hip_bfloat16 bf16;
typedef __attribute__((ext_vector_type(8))) short short8;   // 8 bf16 = 4 VGPRs
typedef __attribute__((ext_vector_type(4))) short bfx4;     // 4 bf16 = 2 VGPRs
typedef __attribute__((ext_vector_type(4))) float floatx4;  // MFMA accumulator

// flags[0] = indices are int64 ; flags[1] = floats are bf16
__device__ inline float ldf(const void* p, int i, int isbf) {
    return isbf ? __bfloat162float(((const bf16*)p)[i]) : ((const float*)p)[i];
}
__device__ inline float4 ld4f(const void* p, int i, int isbf) {  // i % 4 == 0
    if (isbf) {
        const unsigned* q = (const unsigned*)((const short*)p + i);
        unsigned u0 = q[0], u1 = q[1];
        return make_float4(__uint_as_float(u0 << 16), __uint_as_float(u0 & 0xFFFF0000u),
                           __uint_as_float(u1 << 16), __uint_as_float(u1 & 0xFFFF0000u));
    }
    return *(const float4*)((const float*)p + i);
}
__device__ inline void stf(void* p, int i, float v, int isbf) {
    if (isbf) ((bf16*)p)[i] = __float2bfloat16(v);
    else ((float*)p)[i] = v;
}
__device__ inline short f2bfbits(float v) {
    bf16 b = __float2bfloat16(v);
    return *reinterpret_cast<short*>(&b);
}
__device__ inline unsigned char f2fp8(float v) {
    return (unsigned char)(__builtin_amdgcn_cvt_pk_fp8_f32(v, v, 0, false) & 0xFF);
}
__device__ inline int clampN(int v) { return ((unsigned)v < (unsigned)NNODES) ? v : 0; }
__device__ inline int clampG(int v) { return ((unsigned)v < (unsigned)NG) ? v : 0; }

__global__ void detect_kernel(const int* __restrict__ ei, const unsigned* __restrict__ w1,
                              int* __restrict__ flags) {
    __shared__ int nzOdd, insane;
    if (threadIdx.x == 0) { nzOdd = 0; insane = 0; }
    __syncthreads();
    if (ei[2 * threadIdx.x + 1] != 0) atomicAdd(&nzOdd, 1);
    unsigned lo = w1[threadIdx.x] & 0xFFFFu;
    unsigned ex = (lo >> 7) & 0xFFu;
    bool sane = ((lo & 0x7FFFu) == 0u) || (ex >= 90u && ex <= 133u);
    if (!sane) atomicAdd(&insane, 1);
    __syncthreads();
    if (threadIdx.x == 0) {
        flags[0] = (nzOdd == 0) ? 1 : 0;
        flags[1] = (insane == 0) ? 1 : 0;
    }
}

__device__ inline void edge_sd(const int* __restrict__ ei, int e, int E, int is64,
                               int& s_, int& d_) {
    if (e < E) {
        if (is64) { s_ = ei[2 * e]; d_ = ei[2 * E + 2 * e]; }
        else      { s_ = ei[e];     d_ = ei[E + e]; }
    } else {
        s_ = d_ = e - E;  // self-loop
    }
    s_ = clampN(s_);
    d_ = clampN(d_);
}

// ======================= CSR build (once, reused both layers) ================
__global__ void deg_kernel(const int* __restrict__ ei, int* __restrict__ deg,
                           int E, int ET, const int* __restrict__ flags) {
    int e = blockIdx.x * 256 + threadIdx.x;
    if (e >= ET) return;
    int s_, d_;
    edge_sd(ei, e, E, flags[0], s_, d_);
    atomicAdd(&deg[d_], 1);
}

__global__ void scan1_kernel(const int* __restrict__ deg, int* __restrict__ eprefix,
                             int* __restrict__ bsums, int n) {
    __shared__ int sc[256];
    int t = threadIdx.x, i = blockIdx.x * 256 + t;
    int val = (i < n) ? deg[i] : 0;
    sc[t] = val;
    __syncthreads();
    for (int off = 1; off < 256; off <<= 1) {
        int tmp = (t >= off) ? sc[t - off] : 0;
        __syncthreads();
        sc[t] += tmp;
        __syncthreads();
    }
    if (i < n) eprefix[i] = sc[t] - val;
    if (t == 255) bsums[blockIdx.x] = sc[255];
}

__global__ void scan2_kernel(const int* __restrict__ bsums, int* __restrict__ boffs, int nb) {
    __shared__ int sc[256];
    int t = threadIdx.x;
    int val = (t < nb) ? bsums[t] : 0;
    sc[t] = val;
    __syncthreads();
    for (int off = 1; off < 256; off <<= 1) {
        int tmp = (t >= off) ? sc[t - off] : 0;
        __syncthreads();
        sc[t] += tmp;
        __syncthreads();
    }
    if (t < nb) boffs[t] = sc[t] - val;
}

__global__ void scan3_kernel(const int* __restrict__ eprefix, const int* __restrict__ boffs,
                             int* __restrict__ rowptr, int n, int ET) {
    int i = blockIdx.x * 256 + threadIdx.x;
    if (i < n) rowptr[i] = eprefix[i] + boffs[blockIdx.x];
    if (i == n) rowptr[n] = ET;
}

__global__ void scatter_kernel(const int* __restrict__ ei, const int* __restrict__ rowptr,
                               int* __restrict__ cursor, int* __restrict__ srcs,
                               int E, int ET, const int* __restrict__ flags) {
    int e = blockIdx.x * 256 + threadIdx.x;
    if (e >= ET) return;
    int s_, d_;
    edge_sd(ei, e, E, flags[0], s_, d_);
    int pos = atomicAdd(&cursor[d_], 1);
    srcs[rowptr[d_] + pos] = s_;
}

// ========== graph boundaries via binary search (batch is sorted, no atomics) =
__global__ void goff_bs_kernel(const int* __restrict__ bt, int* __restrict__ goff,
                               int* __restrict__ gcnt, const int* __restrict__ flags) {
    int is64 = flags[0];
    int t = threadIdx.x;  // 0..127
    if (t <= NG) {
        int lo = 0, hi = NNODES;
        while (lo < hi) {
            int mid = (lo + hi) >> 1;
            int b = clampG(is64 ? bt[2 * mid] : bt[mid]);
            if (b < t) lo = mid + 1; else hi = mid;
        }
        goff[t] = lo;
    }
    __syncthreads();
    if (t < NG) gcnt[t] = goff[t + 1] - goff[t];
}

// W [256x256] row-major -> fragment-linear B for mfma_f32_16x16x32_bf16:
__global__ void repack_kernel(const void* __restrict__ W, short* __restrict__ Bf,
                              const int* __restrict__ flags) {
    int i = blockIdx.x * 256 + threadIdx.x;  // 65536
    int j = i & 7, lane = (i >> 3) & 63, tile = i >> 9;
    int kt = tile >> 4, ctg = tile & 15;
    int k = kt * 32 + (lane >> 4) * 8 + j;
    int n = ctg * 16 + (lane & 15);
    Bf[i] = f2bfbits(ldf(W, k * NF + n, flags[1]));
}

// ====== MFMA GEMM + fused attention-logit epilogue ===========================
// C8[M,256] (fp8 e4m3) = fp8(A[M,256] @ B[256,256]); a_src/a_dst from fp32 acc.
__global__ __launch_bounds__(256) void gemm_mfma(
        const void* __restrict__ A, const short* __restrict__ Bf,
        unsigned char* __restrict__ C8,
        int M, const int* __restrict__ flags, int aFollows,
        const void* __restrict__ att_s, const void* __restrict__ att_d,
        float* __restrict__ a_src, float* __restrict__ a_dst) {
    int isbf = flags[1];
    int aIsBf = aFollows ? isbf : 1;
    int wave = threadIdx.x >> 6;
    int lane = threadIdx.x & 63;
    int am = lane & 15, aq = lane >> 4;
    int row0 = blockIdx.x * 64;
    float attS[4], attD[4];
    #pragma unroll
    for (int ct = 0; ct < 4; ct++) {
        int col = wave * 64 + ct * 16 + am;
        attS[ct] = ldf(att_s, col, isbf);
        attD[ct] = ldf(att_d, col, isbf);
    }
    int rowA[4];
    #pragma unroll
    for (int rt = 0; rt < 4; rt++) rowA[rt] = min(row0 + rt * 16 + am, M - 1);
    floatx4 acc[4][4];
    #pragma unroll
    for (int i = 0; i < 4; i++)
        #pragma unroll
        for (int j = 0; j < 4; j++) acc[i][j] = (floatx4){0.f, 0.f, 0.f, 0.f};
    for (int kt = 0; kt < 8; kt++) {
        short8 a[4], b[4];
        if (aIsBf) {
            #pragma unroll
            for (int rt = 0; rt < 4; rt++)
                a[rt] = *(const short8*)((const short*)A + rowA[rt] * NF + kt * 32 + aq * 8);
        } else {
            #pragma unroll
            for (int rt = 0; rt < 4; rt++) {
                const float* fp = (const float*)A + rowA[rt] * NF + kt * 32 + aq * 8;
                float4 f0 = *(const float4*)fp;
                float4 f1 = *(const float4*)(fp + 4);
                short8 v;
                v[0] = f2bfbits(f0.x); v[1] = f2bfbits(f0.y);
                v[2] = f2bfbits(f0.z); v[3] = f2bfbits(f0.w);
                v[4] = f2bfbits(f1.x); v[5] = f2bfbits(f1.y);
                v[6] = f2bfbits(f1.z); v[7] = f2bfbits(f1.w);
                a[rt] = v;
            }
        }
        #pragma unroll
        for (int ct = 0; ct < 4; ct++)
            b[ct] = *(const short8*)&Bf[((kt * 16 + wave * 4 + ct) * 64 + lane) * 8];
        #pragma unroll
        for (int rt = 0; rt < 4; rt++)
            #pragma unroll
            for (int ct = 0; ct < 4; ct++)
                acc[rt][ct] = __builtin_amdgcn_mfma_f32_16x16x32_bf16(a[rt], b[ct], acc[rt][ct], 0, 0, 0);
    }
    // C store as fp8 (col = lane&15, row = (lane>>4)*4 + reg)
    int rbase = (lane >> 4) * 4;
    int cbase = wave * 64 + am;
    #pragma unroll
    for (int rt = 0; rt < 4; rt++) {
        #pragma unroll
        for (int r = 0; r < 4; r++) {
            int row = row0 + rt * 16 + rbase + r;
            if (row < M) {
                #pragma unroll
                for (int ct = 0; ct < 4; ct++)
                    C8[row * NF + cbase + ct * 16] = f2fp8(acc[rt][ct][r]);
            }
        }
    }
    // attention-logit epilogue: per (rt,r) reduce 16 col-lanes (fp32 acc)
    #pragma unroll
    for (int rt = 0; rt < 4; rt++) {
        #pragma unroll
        for (int r = 0; r < 4; r++) {
            float ps = 0.f, pd = 0.f;
            #pragma unroll
            for (int ct = 0; ct < 4; ct++) {
                float v = acc[rt][ct][r];
                ps += v * attS[ct];
                pd += v * attD[ct];
            }
            #pragma unroll
            for (int m = 1; m <= 8; m <<= 1) {
                ps += __shfl_xor(ps, m, 64);
                pd += __shfl_xor(pd, m, 64);
            }
            int row = row0 + rt * 16 + rbase + r;
            if (am == 0 && row < M) {
                a_src[row * NH + wave] = ps;
                a_dst[row * NH + wave] = pd;
            }
        }
    }
}

__device__ inline float leaky_clamp(float v) {
    v = v > 0.f ? v : 0.2f * v;
    return fminf(fmaxf(v, -30.f), 30.f);
}

// ---- fused per-dst softmax + aggregate + bias + ELU + residual -------------
// ONE WAVE per dst: lane l owns features {4l..4l+3}; head hh = l>>4 for both
// the alpha-compute assignment and the owned features. fp8 h gather (1 dword
// = 4 features). agg output bf16.
__global__ __launch_bounds__(64) void agg_csr_kernel(
        const int* __restrict__ rowptr, const int* __restrict__ srcs,
        const float* __restrict__ asrc, const float* __restrict__ adst,
        const unsigned char* __restrict__ h8, const void* __restrict__ bias,
        const void* __restrict__ resid, bf16* __restrict__ agg,
        const int* __restrict__ flags, int residFollows) {
    int d = blockIdx.x;
    int l = threadIdx.x;        // 0..63
    int hh = l >> 4;            // head
    int e16 = l & 15;
    int isbf = flags[1];
    int rIsBf = residFollows ? isbf : 1;
    int beg = rowptr[d], end = rowptr[d + 1];
    float ad = adst[d * NH + hh];
    // phase 1: denominator — 16 lanes per head, stride 16
    float part = 0.f;
    for (int k = beg + e16; k < end; k += 16)
        part += __expf(leaky_clamp(asrc[srcs[k] * NH + hh] + ad));
    #pragma unroll
    for (int m = 1; m <= 8; m <<= 1) part += __shfl_xor(part, m, 64);
    float inv = 1.f / fmaxf(part, 1e-30f);
    // phase 2: 16-edge chunks — lane (hh, e16) computes alpha[hh][e16]
    __shared__ float sAl[NH][16];
    __shared__ int sSrc[16];
    float a0 = 0.f, a1 = 0.f, a2 = 0.f, a3 = 0.f;
    for (int cb = beg; cb < end; cb += 16) {
        int nk = min(16, end - cb);
        if (e16 < nk) {
            int s = srcs[cb + e16];
            if (hh == 0) sSrc[e16] = s;
            sAl[hh][e16] = __expf(leaky_clamp(asrc[s * NH + hh] + ad)) * inv;
        }
        __syncthreads();
        for (int k = 0; k < nk; k++) {
            float al = sAl[hh][k];
            unsigned u = *(const unsigned*)&h8[sSrc[k] * NF + 4 * l];
            auto lo = __builtin_amdgcn_cvt_pk_f32_fp8((int)u, false);
            auto hi = __builtin_amdgcn_cvt_pk_f32_fp8((int)u, true);
            a0 += al * lo[0];
            a1 += al * lo[1];
            a2 += al * hi[0];
            a3 += al * hi[1];
        }
        __syncthreads();
    }
    // epilogue: + bias, ELU, + residual; write 4 bf16
    int f0 = 4 * l;
    float4 r = ld4f(resid, d * NF + f0, rIsBf);
    float v0 = a0 + ldf(bias, f0, isbf);
    float v1 = a1 + ldf(bias, f0 + 1, isbf);
    float v2 = a2 + ldf(bias, f0 + 2, isbf);
    float v3 = a3 + ldf(bias, f0 + 3, isbf);
    v0 = v0 > 0.f ? v0 : (__expf(v0) - 1.0f);
    v1 = v1 > 0.f ? v1 : (__expf(v1) - 1.0f);
    v2 = v2 > 0.f ? v2 : (__expf(v2) - 1.0f);
    v3 = v3 > 0.f ? v3 : (__expf(v3) - 1.0f);
    bfx4 o;
    o[0] = f2bfbits(v0 + r.x);
    o[1] = f2bfbits(v1 + r.y);
    o[2] = f2bfbits(v2 + r.z);
    o[3] = f2bfbits(v3 + r.w);
    *(bfx4*)&agg[d * NF + f0] = o;
}

__global__ void bn_stats_kernel(const bf16* __restrict__ x, float* __restrict__ bsum,
                                float* __restrict__ bsumsq) {
    int f = threadIdx.x;
    float s = 0.f, sq = 0.f;
    for (int r = blockIdx.x; r < NNODES; r += gridDim.x) {
        float v = __bfloat162float(x[r * NF + f]);
        s += v;
        sq += v * v;
    }
    atomicAdd(&bsum[f], s);
    atomicAdd(&bsumsq[f], sq);
}

__global__ void bn_norm_kernel(const bf16* __restrict__ x, const float* __restrict__ bsum,
                               const float* __restrict__ bsumsq,
                               const void* __restrict__ gamma, const void* __restrict__ beta,
                               bf16* __restrict__ out, int total, const int* __restrict__ flags) {
    int i = blockIdx.x * blockDim.x + threadIdx.x;
    if (i >= total) return;
    int isbf = flags[1];
    const float invN = 1.0f / (float)NNODES;
    int f = i & (NF - 1);
    float mu = bsum[f] * invN;
    float var = fmaxf(bsumsq[f] * invN - mu * mu, 0.f);
    float v = (__bfloat162float(x[i]) - mu) * rsqrtf(var + 1e-5f);
    out[i] = __float2bfloat16(ldf(gamma, f, isbf) * v + ldf(beta, f, isbf));
}

// ---- pooling: contiguous node slices per graph (batch is sorted) -----------
__global__ void pool2_kernel(const bf16* __restrict__ x, const int* __restrict__ goff,
                             float* __restrict__ pooled) {
    int g = blockIdx.x >> 3, c = blockIdx.x & 7, t = threadIdx.x;
    int beg = goff[g], end = goff[g + 1];
    int len = end - beg;
    if (len <= 0) return;
    int chunk = (len + 7) >> 3;
    int s0 = beg + c * chunk;
    int s1 = min(s0 + chunk, end);
    if (s0 >= s1) return;
    float acc = 0.f;
    for (int n = s0; n < s1; n++) acc += __bfloat162float(x[n * NF + t]);
    atomicAdd(&pooled[g * NF + t], acc);
}

// head: applies layer-2 BN affine to pooled means (BN commutes with mean-pool)
__global__ void head_kernel(const float* __restrict__ pooled, const int* __restrict__ gcnt,
                            const float* __restrict__ bnsum2, const float* __restrict__ bnsq2,
                            const void* __restrict__ gamma2, const void* __restrict__ beta2,
                            const void* __restrict__ fc1w, const void* __restrict__ fc1b,
                            const void* __restrict__ fc2w, const void* __restrict__ fc2b,
                            void* __restrict__ out, const int* __restrict__ flags) {
    int g = blockIdx.x;
    int t = threadIdx.x;  // 64
    int isbf = flags[1];
    __shared__ float p[NF];
    __shared__ float z[64];
    __shared__ float logits[NCLS];
    __shared__ float lse;
    float c = fmaxf((float)gcnt[g], 1.f);
    float invc = 1.f / c;
    const float invN = 1.0f / (float)NNODES;
    for (int i = t; i < NF; i += 64) {
        float mu = bnsum2[i] * invN;
        float var = fmaxf(bnsq2[i] * invN - mu * mu, 0.f);
        float pm = pooled[g * NF + i] * invc;
        p[i] = ldf(gamma2, i, isbf) * ((pm - mu) * rsqrtf(var + 1e-5f)) + ldf(beta2, i, isbf);
    }
    __syncthreads();
    float acc = ldf(fc1b, t, isbf);
    for (int k = 0; k < NF; k++) acc += p[k] * ldf(fc1w, k * 64 + t, isbf);
    z[t] = acc > 0.f ? acc : 0.f;
    __syncthreads();
    if (t < NCLS) {
        float a2 = ldf(fc2b, t, isbf);
        for (int k = 0; k < 64; k++) a2 += z[k] * ldf(fc2w, k * NCLS + t, isbf);
        logits[t] = a2;
    }
    __syncthreads();
    if (t == 0) {
        float mx = logits[0];
        for (int j = 1; j < NCLS; j++) mx = fmaxf(mx, logits[j]);
        float se = 0.f;
        for (int j = 0; j < NCLS; j++) se += expf(logits[j] - mx);
        lse = mx + logf(se);
    }
    __syncthreads();
    if (t < NCLS) stf(out, g * NCLS + t, logits[t] - lse, isbf);
}

extern "C" void kernel_launch(void* const* d_in, const int* in_sizes, int n_in,
                              void* d_out, int out_size, void* d_ws, size_t ws_size,
                              hipStream_t stream) {
    const void* x = d_in[0];
    const int* edge_index = (const int*)d_in[1];
    const int* batch = (const int*)d_in[2];
    const void* W1 = d_in[3];
    const void* att_src1 = d_in[4];
    const void* att_dst1 = d_in[5];
    const void* b1 = d_in[6];
    const void* gamma1 = d_in[7];
    const void* beta1 = d_in[8];
    const void* W2 = d_in[9];
    const void* att_src2 = d_in[10];
    const void* att_dst2 = d_in[11];
    const void* b2 = d_in[12];
    const void* gamma2 = d_in[13];
    const void* beta2 = d_in[14];
    const void* fc1w = d_in[15];
    const void* fc1b = d_in[16];
    const void* fc2w = d_in[17];
    const void* fc2b = d_in[18];

    const int E = in_sizes[1] / 2;     // 400000
    const int ET = E + NNODES;         // + self-loops
    const int NE = NNODES * NF;
    const int NNH = NNODES * NH;
    const int NB = (NNODES + 255) / 256;
    const int NB1 = (NNODES + 1 + 255) / 256;

    // ---- workspace layout ----
    float* ws = (float*)d_ws;
    bf16* aggb = (bf16*)ws;                // N*256 bf16
    float* asrc = ws + NE / 2;             // N*4 (aliases scan scratch early)
    float* adst = asrc + NNH;              // N*4
    int* flags = (int*)(adst + NNH);       // 16
    unsigned char* h8 = (unsigned char*)(flags + 16);  // MPAD*256 fp8
    bf16* l1ob = (bf16*)(h8 + (size_t)MPAD * NF);      // MPAD*256 bf16
    int* rowptr = (int*)(l1ob + (size_t)MPAD * NF);    // N+1 (+pad)
    int* srcs = rowptr + NNODES + 16;      // ET
    int* goff = srcs + ET + 16;            // NG+1
    // zero region (single memset): deg, cursor, gcnt, pooled, bnstat
    int* deg = goff + NG + 1 + 14;
    int* cursor = deg + NNODES;
    int* gcnt = cursor + NNODES;
    float* pooled = (float*)(gcnt + NG);   // 64*256
    float* bnstat = pooled + NG * NF;      // 4*256
    size_t zero_bytes = (size_t)(2 * NNODES + NG) * 4 + (size_t)(NG * NF + 4 * NF) * 4;
    short* Bf1 = (short*)(bnstat + 4 * NF);  // 65536 (outside zero region)
    short* Bf2 = Bf1 + NF * NF;              // 65536
    // scan scratch aliased onto asrc/adst (overwritten later by gemm epilogue)
    int* eprefix = (int*)asrc;
    int* bsums = eprefix + NNODES + 16;
    int* boffs = bsums + 256;

    float* bnsum1 = bnstat;
    float* bnsq1 = bnstat + NF;
    float* bnsum2 = bnstat + 2 * NF;
    float* bnsq2 = bnstat + 3 * NF;

    detect_kernel<<<1, 256, 0, stream>>>(edge_index, (const unsigned*)W1, flags);
    (void)hipMemsetAsync(deg, 0, zero_bytes, stream);

    repack_kernel<<<NF * NF / 256, 256, 0, stream>>>(W1, Bf1, flags);
    repack_kernel<<<NF * NF / 256, 256, 0, stream>>>(W2, Bf2, flags);

    // ---- CSR build + graph boundaries (reused by both layers) ----
    deg_kernel<<<(ET + 255) / 256, 256, 0, stream>>>(edge_index, deg, E, ET, flags);
    scan1_kernel<<<NB, 256, 0, stream>>>(deg, eprefix, bsums, NNODES);
    scan2_kernel<<<1, 256, 0, stream>>>(bsums, boffs, NB);
    scan3_kernel<<<NB1, 256, 0, stream>>>(eprefix, boffs, rowptr, NNODES, ET);
    scatter_kernel<<<(ET + 255) / 256, 256, 0, stream>>>(edge_index, rowptr, cursor, srcs, E, ET, flags);
    goff_bs_kernel<<<1, 128, 0, stream>>>(batch, goff, gcnt, flags);

    // ================= layer 1 =================
    gemm_mfma<<<MPAD / 64, 256, 0, stream>>>(x, Bf1, h8, NNODES, flags, 1,
                                             att_src1, att_dst1, asrc, adst);
    agg_csr_kernel<<<NNODES, 64, 0, stream>>>(rowptr, srcs, asrc, adst, h8, b1, x, aggb, flags, 1);
    bn_stats_kernel<<<512, 256, 0, stream>>>(aggb, bnsum1, bnsq1);
    bn_norm_kernel<<<(NE + 255) / 256, 256, 0, stream>>>(aggb, bnsum1, bnsq1, gamma1, beta1, l1ob, NE, flags);

    // ================= layer 2 =================
    gemm_mfma<<<MPAD / 64, 256, 0, stream>>>(l1ob, Bf2, h8, NNODES, flags, 0,
                                             att_src2, att_dst2, asrc, adst);
    agg_csr_kernel<<<NNODES, 64, 0, stream>>>(rowptr, srcs, asrc, adst, h8, b2, l1ob, aggb, flags, 0);
    bn_stats_kernel<<<512, 256, 0, stream>>>(aggb, bnsum2, bnsq2);
    // no bn_norm for layer 2: BN affine applied to pooled means in head

    // ================= pool + head =================
    pool2_kernel<<<NG * 8, 256, 0, stream>>>(aggb, goff, pooled);
    head_kernel<<<NG, 64, 0, stream>>>(pooled, gcnt, bnsum2, bnsq2, gamma2, beta2,
                                       fc1w, fc1b, fc2w, fc2b, d_out, flags);
}

// Round 11
// 488.229 us; speedup vs baseline: 4.5195x; 1.0126x over previous
//
#include <hip/hip_runtime.h>
#include <hip/hip_bf16.h>

#define NNODES 50000
#define NF 256
#define NH 4
#define NG 64
#define NCLS 10
#define MPAD 50048  // NNODES rounded up to multiple of 64 (gemm row padding)

typedef __hip_bfloat16 bf16;
typedef __attribute__((ext_vector_type(8))) short short8;   // 8 bf16 = 4 VGPRs
typedef __attribute__((ext_vector_type(4))) short bfx4;     // 4 bf16 = 2 VGPRs
typedef __attribute__((ext_vector_type(4))) float floatx4;  // MFMA accumulator

// flags[0] = indices are int64 ; flags[1] = floats are bf16
__device__ inline float ldf(const void* p, int i, int isbf) {
    return isbf ? __bfloat162float(((const bf16*)p)[i]) : ((const float*)p)[i];
}
__device__ inline float4 ld4f(const void* p, int i, int isbf) {  // i % 4 == 0
    if (isbf) {
        const unsigned* q = (const unsigned*)((const short*)p + i);
        unsigned u0 = q[0], u1 = q[1];
        return make_float4(__uint_as_float(u0 << 16), __uint_as_float(u0 & 0xFFFF0000u),
                           __uint_as_float(u1 << 16), __uint_as_float(u1 & 0xFFFF0000u));
    }
    return *(const float4*)((const float*)p + i);
}
__device__ inline void stf(void* p, int i, float v, int isbf) {
    if (isbf) ((bf16*)p)[i] = __float2bfloat16(v);
    else ((float*)p)[i] = v;
}
__device__ inline short f2bfbits(float v) {
    bf16 b = __float2bfloat16(v);
    return *reinterpret_cast<short*>(&b);
}
__device__ inline unsigned char f2fp8(float v) {
    return (unsigned char)(__builtin_amdgcn_cvt_pk_fp8_f32(v, v, 0, false) & 0xFF);
}
__device__ inline int clampN(int v) { return ((unsigned)v < (unsigned)NNODES) ? v : 0; }
__device__ inline int clampG(int v) { return ((unsigned)v < (unsigned)NG) ? v : 0; }

__global__ void detect_kernel(const int* __restrict__ ei, const unsigned* __restrict__ w1,
                              int* __restrict__ flags) {
    __shared__ int nzOdd, insane;
    if (threadIdx.x == 0) { nzOdd = 0; insane = 0; }
    __syncthreads();
    if (ei[2 * threadIdx.x + 1] != 0) atomicAdd(&nzOdd, 1);
    unsigned lo = w1[threadIdx.x] & 0xFFFFu;
    unsigned ex = (lo >> 7) & 0xFFu;
    bool sane = ((lo & 0x7FFFu) == 0u) || (ex >= 90u && ex <= 133u);
    if (!sane) atomicAdd(&insane, 1);
    __syncthreads();
    if (threadIdx.x == 0) {
        flags[0] = (nzOdd == 0) ? 1 : 0;
        flags[1] = (insane == 0) ? 1 : 0;
    }
}

__device__ inline void edge_sd(const int* __restrict__ ei, int e, int E, int is64,
                               int& s_, int& d_) {
    if (e < E) {
        if (is64) { s_ = ei[2 * e]; d_ = ei[2 * E + 2 * e]; }
        else      { s_ = ei[e];     d_ = ei[E + e]; }
    } else {
        s_ = d_ = e - E;  // self-loop
    }
    s_ = clampN(s_);
    d_ = clampN(d_);
}

// ======================= CSR build (once, reused both layers) ================
__global__ void deg_kernel(const int* __restrict__ ei, int* __restrict__ deg,
                           int E, int ET, const int* __restrict__ flags) {
    int e = blockIdx.x * 256 + threadIdx.x;
    if (e >= ET) return;
    int s_, d_;
    edge_sd(ei, e, E, flags[0], s_, d_);
    atomicAdd(&deg[d_], 1);
}

__global__ void scan1_kernel(const int* __restrict__ deg, int* __restrict__ eprefix,
                             int* __restrict__ bsums, int n) {
    __shared__ int sc[256];
    int t = threadIdx.x, i = blockIdx.x * 256 + t;
    int val = (i < n) ? deg[i] : 0;
    sc[t] = val;
    __syncthreads();
    for (int off = 1; off < 256; off <<= 1) {
        int tmp = (t >= off) ? sc[t - off] : 0;
        __syncthreads();
        sc[t] += tmp;
        __syncthreads();
    }
    if (i < n) eprefix[i] = sc[t] - val;
    if (t == 255) bsums[blockIdx.x] = sc[255];
}

__global__ void scan2_kernel(const int* __restrict__ bsums, int* __restrict__ boffs, int nb) {
    __shared__ int sc[256];
    int t = threadIdx.x;
    int val = (t < nb) ? bsums[t] : 0;
    sc[t] = val;
    __syncthreads();
    for (int off = 1; off < 256; off <<= 1) {
        int tmp = (t >= off) ? sc[t - off] : 0;
        __syncthreads();
        sc[t] += tmp;
        __syncthreads();
    }
    if (t < nb) boffs[t] = sc[t] - val;
}

__global__ void scan3_kernel(const int* __restrict__ eprefix, const int* __restrict__ boffs,
                             int* __restrict__ rowptr, int n, int ET) {
    int i = blockIdx.x * 256 + threadIdx.x;
    if (i < n) rowptr[i] = eprefix[i] + boffs[blockIdx.x];
    if (i == n) rowptr[n] = ET;
}

__global__ void scatter_kernel(const int* __restrict__ ei, const int* __restrict__ rowptr,
                               int* __restrict__ cursor, int* __restrict__ srcs,
                               int E, int ET, const int* __restrict__ flags) {
    int e = blockIdx.x * 256 + threadIdx.x;
    if (e >= ET) return;
    int s_, d_;
    edge_sd(ei, e, E, flags[0], s_, d_);
    int pos = atomicAdd(&cursor[d_], 1);
    srcs[rowptr[d_] + pos] = s_;
}

// ========== graph boundaries via binary search (batch is sorted, no atomics) =
__global__ void goff_bs_kernel(const int* __restrict__ bt, int* __restrict__ goff,
                               int* __restrict__ gcnt, const int* __restrict__ flags) {
    int is64 = flags[0];
    int t = threadIdx.x;  // 0..127
    if (t <= NG) {
        int lo = 0, hi = NNODES;
        while (lo < hi) {
            int mid = (lo + hi) >> 1;
            int b = clampG(is64 ? bt[2 * mid] : bt[mid]);
            if (b < t) lo = mid + 1; else hi = mid;
        }
        goff[t] = lo;
    }
    __syncthreads();
    if (t < NG) gcnt[t] = goff[t + 1] - goff[t];
}

// W [256x256] row-major -> fragment-linear B for mfma_f32_16x16x32_bf16:
__global__ void repack_kernel(const void* __restrict__ W, short* __restrict__ Bf,
                              const int* __restrict__ flags) {
    int i = blockIdx.x * 256 + threadIdx.x;  // 65536
    int j = i & 7, lane = (i >> 3) & 63, tile = i >> 9;
    int kt = tile >> 4, ctg = tile & 15;
    int k = kt * 32 + (lane >> 4) * 8 + j;
    int n = ctg * 16 + (lane & 15);
    Bf[i] = f2bfbits(ldf(W, k * NF + n, flags[1]));
}

// ====== MFMA GEMM + fused attention-logit epilogue ===========================
// C8[M,256] (fp8 e4m3) = fp8(A[M,256] @ B[256,256]); a_src/a_dst from fp32 acc.
// Block tile 32 rows x 256 cols, 4 waves (wave w: cols w*64..+63, 2x4 MFMA tiles).
// K-loop software-pipelined: kt+1 fragments prefetched before kt's MFMAs.
__global__ __launch_bounds__(256) void gemm_mfma(
        const void* __restrict__ A, const short* __restrict__ Bf,
        unsigned char* __restrict__ C8,
        int M, const int* __restrict__ flags, int aFollows,
        const void* __restrict__ att_s, const void* __restrict__ att_d,
        float* __restrict__ a_src, float* __restrict__ a_dst) {
    int isbf = flags[1];
    int aIsBf = aFollows ? isbf : 1;
    int wave = threadIdx.x >> 6;
    int lane = threadIdx.x & 63;
    int am = lane & 15, aq = lane >> 4;
    int row0 = blockIdx.x * 32;
    float attS[4], attD[4];
    #pragma unroll
    for (int ct = 0; ct < 4; ct++) {
        int col = wave * 64 + ct * 16 + am;
        attS[ct] = ldf(att_s, col, isbf);
        attD[ct] = ldf(att_d, col, isbf);
    }
    int rowA[2];
    #pragma unroll
    for (int rt = 0; rt < 2; rt++) rowA[rt] = min(row0 + rt * 16 + am, M - 1);

    auto loadA = [&](short8* a, int kt) {
        if (aIsBf) {
            #pragma unroll
            for (int rt = 0; rt < 2; rt++)
                a[rt] = *(const short8*)((const short*)A + rowA[rt] * NF + kt * 32 + aq * 8);
        } else {
            #pragma unroll
            for (int rt = 0; rt < 2; rt++) {
                const float* fp = (const float*)A + rowA[rt] * NF + kt * 32 + aq * 8;
                float4 f0 = *(const float4*)fp;
                float4 f1 = *(const float4*)(fp + 4);
                short8 v;
                v[0] = f2bfbits(f0.x); v[1] = f2bfbits(f0.y);
                v[2] = f2bfbits(f0.z); v[3] = f2bfbits(f0.w);
                v[4] = f2bfbits(f1.x); v[5] = f2bfbits(f1.y);
                v[6] = f2bfbits(f1.z); v[7] = f2bfbits(f1.w);
                a[rt] = v;
            }
        }
    };
    auto loadB = [&](short8* b, int kt) {
        #pragma unroll
        for (int ct = 0; ct < 4; ct++)
            b[ct] = *(const short8*)&Bf[((kt * 16 + wave * 4 + ct) * 64 + lane) * 8];
    };

    floatx4 acc[2][4];
    #pragma unroll
    for (int i = 0; i < 2; i++)
        #pragma unroll
        for (int j = 0; j < 4; j++) acc[i][j] = (floatx4){0.f, 0.f, 0.f, 0.f};

    short8 a[2], b[4];
    loadA(a, 0);
    loadB(b, 0);
    for (int kt = 0; kt < 8; kt++) {
        short8 an[2], bn[4];
        if (kt < 7) {
            loadA(an, kt + 1);
            loadB(bn, kt + 1);
        }
        #pragma unroll
        for (int rt = 0; rt < 2; rt++)
            #pragma unroll
            for (int ct = 0; ct < 4; ct++)
                acc[rt][ct] = __builtin_amdgcn_mfma_f32_16x16x32_bf16(a[rt], b[ct], acc[rt][ct], 0, 0, 0);
        if (kt < 7) {
            a[0] = an[0]; a[1] = an[1];
            b[0] = bn[0]; b[1] = bn[1]; b[2] = bn[2]; b[3] = bn[3];
        }
    }
    // C store as fp8 (col = lane&15, row = (lane>>4)*4 + reg)
    int rbase = (lane >> 4) * 4;
    int cbase = wave * 64 + am;
    #pragma unroll
    for (int rt = 0; rt < 2; rt++) {
        #pragma unroll
        for (int r = 0; r < 4; r++) {
            int row = row0 + rt * 16 + rbase + r;
            if (row < M) {
                #pragma unroll
                for (int ct = 0; ct < 4; ct++)
                    C8[row * NF + cbase + ct * 16] = f2fp8(acc[rt][ct][r]);
            }
        }
    }
    // attention-logit epilogue: per (rt,r) reduce 16 col-lanes (fp32 acc)
    #pragma unroll
    for (int rt = 0; rt < 2; rt++) {
        #pragma unroll
        for (int r = 0; r < 4; r++) {
            float ps = 0.f, pd = 0.f;
            #pragma unroll
            for (int ct = 0; ct < 4; ct++) {
                float v = acc[rt][ct][r];
                ps += v * attS[ct];
                pd += v * attD[ct];
            }
            #pragma unroll
            for (int m = 1; m <= 8; m <<= 1) {
                ps += __shfl_xor(ps, m, 64);
                pd += __shfl_xor(pd, m, 64);
            }
            int row = row0 + rt * 16 + rbase + r;
            if (am == 0 && row < M) {
                a_src[row * NH + wave] = ps;
                a_dst[row * NH + wave] = pd;
            }
        }
    }
}

__device__ inline float leaky_clamp(float v) {
    v = v > 0.f ? v : 0.2f * v;
    return fminf(fmaxf(v, -30.f), 30.f);
}

// ---- fused per-dst softmax + aggregate + bias + ELU + residual -------------
// ONE WAVE per dst: lane l owns features {4l..4l+3}; head hh = l>>4. fp8 gather.
__global__ __launch_bounds__(64) void agg_csr_kernel(
        const int* __restrict__ rowptr, const int* __restrict__ srcs,
        const float* __restrict__ asrc, const float* __restrict__ adst,
        const unsigned char* __restrict__ h8, const void* __restrict__ bias,
        const void* __restrict__ resid, bf16* __restrict__ agg,
        const int* __restrict__ flags, int residFollows) {
    int d = blockIdx.x;
    int l = threadIdx.x;        // 0..63
    int hh = l >> 4;            // head
    int e16 = l & 15;
    int isbf = flags[1];
    int rIsBf = residFollows ? isbf : 1;
    int beg = rowptr[d], end = rowptr[d + 1];
    float ad = adst[d * NH + hh];
    float part = 0.f;
    for (int k = beg + e16; k < end; k += 16)
        part += __expf(leaky_clamp(asrc[srcs[k] * NH + hh] + ad));
    #pragma unroll
    for (int m = 1; m <= 8; m <<= 1) part += __shfl_xor(part, m, 64);
    float inv = 1.f / fmaxf(part, 1e-30f);
    __shared__ float sAl[NH][16];
    __shared__ int sSrc[16];
    float a0 = 0.f, a1 = 0.f, a2 = 0.f, a3 = 0.f;
    for (int cb = beg; cb < end; cb += 16) {
        int nk = min(16, end - cb);
        if (e16 < nk) {
            int s = srcs[cb + e16];
            if (hh == 0) sSrc[e16] = s;
            sAl[hh][e16] = __expf(leaky_clamp(asrc[s * NH + hh] + ad)) * inv;
        }
        __syncthreads();
        for (int k = 0; k < nk; k++) {
            float al = sAl[hh][k];
            unsigned u = *(const unsigned*)&h8[sSrc[k] * NF + 4 * l];
            auto lo = __builtin_amdgcn_cvt_pk_f32_fp8((int)u, false);
            auto hi = __builtin_amdgcn_cvt_pk_f32_fp8((int)u, true);
            a0 += al * lo[0];
            a1 += al * lo[1];
            a2 += al * hi[0];
            a3 += al * hi[1];
        }
        __syncthreads();
    }
    int f0 = 4 * l;
    float4 r = ld4f(resid, d * NF + f0, rIsBf);
    float v0 = a0 + ldf(bias, f0, isbf);
    float v1 = a1 + ldf(bias, f0 + 1, isbf);
    float v2 = a2 + ldf(bias, f0 + 2, isbf);
    float v3 = a3 + ldf(bias, f0 + 3, isbf);
    v0 = v0 > 0.f ? v0 : (__expf(v0) - 1.0f);
    v1 = v1 > 0.f ? v1 : (__expf(v1) - 1.0f);
    v2 = v2 > 0.f ? v2 : (__expf(v2) - 1.0f);
    v3 = v3 > 0.f ? v3 : (__expf(v3) - 1.0f);
    bfx4 o;
    o[0] = f2bfbits(v0 + r.x);
    o[1] = f2bfbits(v1 + r.y);
    o[2] = f2bfbits(v2 + r.z);
    o[3] = f2bfbits(v3 + r.w);
    *(bfx4*)&agg[d * NF + f0] = o;
}

__global__ void bn_stats_kernel(const bf16* __restrict__ x, float* __restrict__ bsum,
                                float* __restrict__ bsumsq) {
    int f = threadIdx.x;
    float s = 0.f, sq = 0.f;
    for (int r = blockIdx.x; r < NNODES; r += gridDim.x) {
        float v = __bfloat162float(x[r * NF + f]);
        s += v;
        sq += v * v;
    }
    atomicAdd(&bsum[f], s);
    atomicAdd(&bsumsq[f], sq);
}

__global__ void bn_norm_kernel(const bf16* __restrict__ x, const float* __restrict__ bsum,
                               const float* __restrict__ bsumsq,
                               const void* __restrict__ gamma, const void* __restrict__ beta,
                               bf16* __restrict__ out, int total, const int* __restrict__ flags) {
    int i = blockIdx.x * blockDim.x + threadIdx.x;
    if (i >= total) return;
    int isbf = flags[1];
    const float invN = 1.0f / (float)NNODES;
    int f = i & (NF - 1);
    float mu = bsum[f] * invN;
    float var = fmaxf(bsumsq[f] * invN - mu * mu, 0.f);
    float v = (__bfloat162float(x[i]) - mu) * rsqrtf(var + 1e-5f);
    out[i] = __float2bfloat16(ldf(gamma, f, isbf) * v + ldf(beta, f, isbf));
}

// ---- pooling: contiguous node slices per graph (batch is sorted) -----------
__global__ void pool2_kernel(const bf16* __restrict__ x, const int* __restrict__ goff,
                             float* __restrict__ pooled) {
    int g = blockIdx.x >> 3, c = blockIdx.x & 7, t = threadIdx.x;
    int beg = goff[g], end = goff[g + 1];
    int len = end - beg;
    if (len <= 0) return;
    int chunk = (len + 7) >> 3;
    int s0 = beg + c * chunk;
    int s1 = min(s0 + chunk, end);
    if (s0 >= s1) return;
    float acc = 0.f;
    for (int n = s0; n < s1; n++) acc += __bfloat162float(x[n * NF + t]);
    atomicAdd(&pooled[g * NF + t], acc);
}

// head: applies layer-2 BN affine to pooled means (BN commutes with mean-pool)
__global__ void head_kernel(const float* __restrict__ pooled, const int* __restrict__ gcnt,
                            const float* __restrict__ bnsum2, const float* __restrict__ bnsq2,
                            const void* __restrict__ gamma2, const void* __restrict__ beta2,
                            const void* __restrict__ fc1w, const void* __restrict__ fc1b,
                            const void* __restrict__ fc2w, const void* __restrict__ fc2b,
                            void* __restrict__ out, const int* __restrict__ flags) {
    int g = blockIdx.x;
    int t = threadIdx.x;  // 64
    int isbf = flags[1];
    __shared__ float p[NF];
    __shared__ float z[64];
    __shared__ float logits[NCLS];
    __shared__ float lse;
    float c = fmaxf((float)gcnt[g], 1.f);
    float invc = 1.f / c;
    const float invN = 1.0f / (float)NNODES;
    for (int i = t; i < NF; i += 64) {
        float mu = bnsum2[i] * invN;
        float var = fmaxf(bnsq2[i] * invN - mu * mu, 0.f);
        float pm = pooled[g * NF + i] * invc;
        p[i] = ldf(gamma2, i, isbf) * ((pm - mu) * rsqrtf(var + 1e-5f)) + ldf(beta2, i, isbf);
    }
    __syncthreads();
    float acc = ldf(fc1b, t, isbf);
    for (int k = 0; k < NF; k++) acc += p[k] * ldf(fc1w, k * 64 + t, isbf);
    z[t] = acc > 0.f ? acc : 0.f;
    __syncthreads();
    if (t < NCLS) {
        float a2 = ldf(fc2b, t, isbf);
        for (int k = 0; k < 64; k++) a2 += z[k] * ldf(fc2w, k * NCLS + t, isbf);
        logits[t] = a2;
    }
    __syncthreads();
    if (t == 0) {
        float mx = logits[0];
        for (int j = 1; j < NCLS; j++) mx = fmaxf(mx, logits[j]);
        float se = 0.f;
        for (int j = 0; j < NCLS; j++) se += expf(logits[j] - mx);
        lse = mx + logf(se);
    }
    __syncthreads();
    if (t < NCLS) stf(out, g * NCLS + t, logits[t] - lse, isbf);
}

extern "C" void kernel_launch(void* const* d_in, const int* in_sizes, int n_in,
                              void* d_out, int out_size, void* d_ws, size_t ws_size,
                              hipStream_t stream) {
    const void* x = d_in[0];
    const int* edge_index = (const int*)d_in[1];
    const int* batch = (const int*)d_in[2];
    const void* W1 = d_in[3];
    const void* att_src1 = d_in[4];
    const void* att_dst1 = d_in[5];
    const void* b1 = d_in[6];
    const void* gamma1 = d_in[7];
    const void* beta1 = d_in[8];
    const void* W2 = d_in[9];
    const void* att_src2 = d_in[10];
    const void* att_dst2 = d_in[11];
    const void* b2 = d_in[12];
    const void* gamma2 = d_in[13];
    const void* beta2 = d_in[14];
    const void* fc1w = d_in[15];
    const void* fc1b = d_in[16];
    const void* fc2w = d_in[17];
    const void* fc2b = d_in[18];

    const int E = in_sizes[1] / 2;     // 400000
    const int ET = E + NNODES;         // + self-loops
    const int NE = NNODES * NF;
    const int NNH = NNODES * NH;
    const int NB = (NNODES + 255) / 256;
    const int NB1 = (NNODES + 1 + 255) / 256;

    // ---- workspace layout ----
    float* ws = (float*)d_ws;
    bf16* aggb = (bf16*)ws;                // N*256 bf16
    float* asrc = ws + NE / 2;             // N*4 (aliases scan scratch early)
    float* adst = asrc + NNH;              // N*4
    int* flags = (int*)(adst + NNH);       // 16
    unsigned char* h8 = (unsigned char*)(flags + 16);  // MPAD*256 fp8
    bf16* l1ob = (bf16*)(h8 + (size_t)MPAD * NF);      // MPAD*256 bf16
    int* rowptr = (int*)(l1ob + (size_t)MPAD * NF);    // N+1 (+pad)
    int* srcs = rowptr + NNODES + 16;      // ET
    int* goff = srcs + ET + 16;            // NG+1
    // zero region (single memset): deg, cursor, gcnt, pooled, bnstat
    int* deg = goff + NG + 1 + 14;
    int* cursor = deg + NNODES;
    int* gcnt = cursor + NNODES;
    float* pooled = (float*)(gcnt + NG);   // 64*256
    float* bnstat = pooled + NG * NF;      // 4*256
    size_t zero_bytes = (size_t)(2 * NNODES + NG) * 4 + (size_t)(NG * NF + 4 * NF) * 4;
    short* Bf1 = (short*)(bnstat + 4 * NF);  // 65536 (outside zero region)
    short* Bf2 = Bf1 + NF * NF;              // 65536
    // scan scratch aliased onto asrc/adst (overwritten later by gemm epilogue)
    int* eprefix = (int*)asrc;
    int* bsums = eprefix + NNODES + 16;
    int* boffs = bsums + 256;

    float* bnsum1 = bnstat;
    float* bnsq1 = bnstat + NF;
    float* bnsum2 = bnstat + 2 * NF;
    float* bnsq2 = bnstat + 3 * NF;

    detect_kernel<<<1, 256, 0, stream>>>(edge_index, (const unsigned*)W1, flags);
    (void)hipMemsetAsync(deg, 0, zero_bytes, stream);

    repack_kernel<<<NF * NF / 256, 256, 0, stream>>>(W1, Bf1, flags);
    repack_kernel<<<NF * NF / 256, 256, 0, stream>>>(W2, Bf2, flags);

    // ---- CSR build + graph boundaries (reused by both layers) ----
    deg_kernel<<<(ET + 255) / 256, 256, 0, stream>>>(edge_index, deg, E, ET, flags);
    scan1_kernel<<<NB, 256, 0, stream>>>(deg, eprefix, bsums, NNODES);
    scan2_kernel<<<1, 256, 0, stream>>>(bsums, boffs, NB);
    scan3_kernel<<<NB1, 256, 0, stream>>>(eprefix, boffs, rowptr, NNODES, ET);
    scatter_kernel<<<(ET + 255) / 256, 256, 0, stream>>>(edge_index, rowptr, cursor, srcs, E, ET, flags);
    goff_bs_kernel<<<1, 128, 0, stream>>>(batch, goff, gcnt, flags);

    // ================= layer 1 =================
    gemm_mfma<<<MPAD / 32, 256, 0, stream>>>(x, Bf1, h8, NNODES, flags, 1,
                                             att_src1, att_dst1, asrc, adst);
    agg_csr_kernel<<<NNODES, 64, 0, stream>>>(rowptr, srcs, asrc, adst, h8, b1, x, aggb, flags, 1);
    bn_stats_kernel<<<512, 256, 0, stream>>>(aggb, bnsum1, bnsq1);
    bn_norm_kernel<<<(NE + 255) / 256, 256, 0, stream>>>(aggb, bnsum1, bnsq1, gamma1, beta1, l1ob, NE, flags);

    // ================= layer 2 =================
    gemm_mfma<<<MPAD / 32, 256, 0, stream>>>(l1ob, Bf2, h8, NNODES, flags, 0,
                                             att_src2, att_dst2, asrc, adst);
    agg_csr_kernel<<<NNODES, 64, 0, stream>>>(rowptr, srcs, asrc, adst, h8, b2, l1ob, aggb, flags, 0);
    bn_stats_kernel<<<512, 256, 0, stream>>>(aggb, bnsum2, bnsq2);
    // no bn_norm for layer 2: BN affine applied to pooled means in head

    // ================= pool + head =================
    pool2_kernel<<<NG * 8, 256, 0, stream>>>(aggb, goff, pooled);
    head_kernel<<<NG, 64, 0, stream>>>(pooled, gcnt, bnsum2, bnsq2, gamma2, beta2,
                                       fc1w, fc1b, fc2w, fc2b, d_out, flags);
}